// Round 4
// baseline (163.390 us; speedup 1.0000x reference)
//
#include <hip/hip_runtime.h>
#include <stdint.h>

// B=2, S=2048, D=1024, H=16, HD=64
typedef unsigned short u16;
typedef unsigned int u32;
typedef __bf16 bf16x8 __attribute__((ext_vector_type(8)));
typedef float f32x4 __attribute__((ext_vector_type(4)));
typedef unsigned short u16x8 __attribute__((ext_vector_type(8)));
typedef unsigned short u16x4 __attribute__((ext_vector_type(4)));

#define QSCALE 0.1803368801111204f  // 0.125 * log2(e): folded into Wq/bq so softmax uses exp2

static __device__ __forceinline__ u16 f2bf(float f) {
  unsigned u = __builtin_bit_cast(unsigned, f);
  u += 0x7fffu + ((u >> 16) & 1u);   // RNE
  return (u16)(u >> 16);
}

static __device__ __forceinline__ bf16x8 ldfrag(const u16* p) {
  return *reinterpret_cast<const bf16x8*>(p);
}

static __device__ __forceinline__ void gll16(const u16* g, u16* l) {
  __builtin_amdgcn_global_load_lds(
      (const __attribute__((address_space(1))) void*)g,
      (__attribute__((address_space(3))) void*)l, 16, 0, 0);
}

static __device__ __forceinline__ u32 cvt_pk_bf16(float lo, float hi) {
  u32 r;
  asm("v_cvt_pk_bf16_f32 %0, %1, %2" : "=v"(r) : "v"(lo), "v"(hi));
  return r;
}

// V-frag LDS swizzle: XOR bits {3,6,7} of the 16B-unit index into bits {0,2:1}.
// Involution; write-side spreads the 8-way-conflicting slots across all 32 banks,
// read-side stays a permutation of each wave's contiguous 1KB (conflict-free).
static __device__ __forceinline__ int vswz(int L) {
  return L ^ ((((L >> 6) & 3) << 1) | ((L >> 3) & 1));
}

// ---------------- cast x: fp32 -> bf16, [4096][1024] ----------------
__global__ __launch_bounds__(256) void cast_x_kernel(const float* __restrict__ x,
                                                     u16* __restrict__ xb) {
  int i = (blockIdx.x * 256 + threadIdx.x) * 8;
  const float4* p = reinterpret_cast<const float4*>(x + i);
  float4 a = p[0], b = p[1];
  u16x8 o;
  o[0] = f2bf(a.x); o[1] = f2bf(a.y); o[2] = f2bf(a.z); o[3] = f2bf(a.w);
  o[4] = f2bf(b.x); o[5] = f2bf(b.y); o[6] = f2bf(b.z); o[7] = f2bf(b.w);
  *reinterpret_cast<u16x8*>(xb + i) = o;
}

// -------- transpose + cast W [k][n] fp32 -> Wt [n][k] bf16 (z picks Wq/Wk/Wv/Wo) --------
__global__ __launch_bounds__(256) void transpose_w_kernel(
    const float* __restrict__ Wq, const float* __restrict__ Wk,
    const float* __restrict__ Wv, const float* __restrict__ Wo,
    u16* __restrict__ WT) {
  __shared__ float tile[64][65];
  int z = blockIdx.z;
  const float* W = (z == 0) ? Wq : (z == 1) ? Wk : (z == 2) ? Wv : Wo;
  float wscale = (z == 0) ? QSCALE : 1.0f;
  u16* out = WT + (size_t)z * 1024 * 1024;
  int k0 = blockIdx.y * 64, n0 = blockIdx.x * 64;
  int t = threadIdx.x;
  int rr = t >> 4;         // 0..15
  int cc = (t & 15) * 4;   // 0..60
#pragma unroll
  for (int j = 0; j < 4; ++j) {
    int r = rr + 16 * j;
    float4 v = *reinterpret_cast<const float4*>(W + (size_t)(k0 + r) * 1024 + n0 + cc);
    tile[r][cc + 0] = v.x; tile[r][cc + 1] = v.y;
    tile[r][cc + 2] = v.z; tile[r][cc + 3] = v.w;
  }
  __syncthreads();
#pragma unroll
  for (int j = 0; j < 4; ++j) {
    int nl = rr + 16 * j;
    u16x4 o;
#pragma unroll
    for (int i2 = 0; i2 < 4; ++i2) o[i2] = f2bf(tile[cc + i2][nl] * wscale);
    *reinterpret_cast<u16x4*>(out + (size_t)(n0 + nl) * 1024 + k0 + cc) = o;
  }
}

// ---------------- generic bf16 GEMM: C[4096][1024] = A @ Wt^T + bias ----------------
template <int MODE>
static __device__ __forceinline__ void gemm_body(const u16* __restrict__ A,
                                                 const u16* __restrict__ Wt,
                                                 const float* __restrict__ bias,
                                                 float bscale,
                                                 void* __restrict__ Out) {
  __shared__ u16 As[128 * 32];
  __shared__ u16 Bs[128 * 32];
  int t = threadIdx.x;
  int lane = t & 63, wave = t >> 6;
  int g = lane >> 4, c = lane & 15;
  int m0 = blockIdx.y * 128, n0 = blockIdx.x * 128;
  int wm = (wave >> 1) * 64, wn = (wave & 1) * 64;

  f32x4 acc[4][4] = {};

  const u16* Ag = A + (size_t)(m0 + (t >> 2)) * 1024 + (t & 3) * 8;
  const u16* Bg = Wt + (size_t)(n0 + (t >> 2)) * 1024 + (t & 3) * 8;
  u16* Asd = As + t * 8;
  u16* Bsd = Bs + t * 8;

  for (int k0 = 0; k0 < 1024; k0 += 32) {
    gll16(Ag + k0, Asd);
    gll16(Ag + 64 * 1024 + k0, Asd + 64 * 32);
    gll16(Bg + k0, Bsd);
    gll16(Bg + 64 * 1024 + k0, Bsd + 64 * 32);
    __syncthreads();
    bf16x8 af[4], bfr[4];
#pragma unroll
    for (int i = 0; i < 4; ++i) {
      af[i]  = ldfrag(As + (wm + 16 * i + c) * 32 + g * 8);
      bfr[i] = ldfrag(Bs + (wn + 16 * i + c) * 32 + g * 8);
    }
#pragma unroll
    for (int i = 0; i < 4; ++i)
#pragma unroll
      for (int j = 0; j < 4; ++j)
        acc[i][j] = __builtin_amdgcn_mfma_f32_16x16x32_bf16(af[i], bfr[j], acc[i][j], 0, 0, 0);
    __syncthreads();
  }

  if (MODE == 0) {
    u16* out = (u16*)Out;
#pragma unroll
    for (int i = 0; i < 4; ++i) {
      int mb = m0 + wm + 16 * i + g * 4;
#pragma unroll
      for (int j = 0; j < 4; ++j) {
        int n = n0 + wn + 16 * j + c;
        float bv = bias[n] * bscale;
        int h = n >> 6, d = n & 63;
#pragma unroll
        for (int r = 0; r < 4; ++r) {
          int m = mb + r;
          int b = m >> 11, s = m & 2047;   // m = b*2048 + s
          out[((size_t)(b * 16 + h) * 2048 + s) * 64 + d] = f2bf(acc[i][j][r] + bv);
        }
      }
    }
  } else {
    float* out = (float*)Out;
#pragma unroll
    for (int i = 0; i < 4; ++i) {
      int mb = m0 + wm + 16 * i + g * 4;
#pragma unroll
      for (int j = 0; j < 4; ++j) {
        int n = n0 + wn + 16 * j + c;
        float bv = bias[n];
#pragma unroll
        for (int r = 0; r < 4; ++r)
          out[(size_t)(mb + r) * 1024 + n] = acc[i][j][r] + bv;
      }
    }
  }
}

__global__ __launch_bounds__(256) void qkv_gemm_kernel(
    const u16* __restrict__ xb, const u16* __restrict__ WT,
    const float* __restrict__ bq, const float* __restrict__ bk,
    const float* __restrict__ bv,
    u16* __restrict__ Q, u16* __restrict__ K, u16* __restrict__ V) {
  int z = blockIdx.z;
  const u16* Wt = WT + (size_t)z * 1024 * 1024;
  const float* bias = (z == 0) ? bq : (z == 1) ? bk : bv;
  float bscale = (z == 0) ? QSCALE : 1.0f;
  u16* out = (z == 0) ? Q : (z == 1) ? K : V;
  gemm_body<0>(xb, Wt, bias, bscale, out);
}

__global__ __launch_bounds__(256) void oproj_kernel(
    const u16* __restrict__ attnb, const u16* __restrict__ WoT,
    const float* __restrict__ bo, float* __restrict__ out) {
  gemm_body<1>(attnb, WoT, bo, 1.0f, out);
}

// ---------------- flash attention (swapped-QK, frag-native LDS, KVBLK=64, QBLK=32/wave) ----
// Q,K,V: [B,H,S,HD] bf16 (Q pre-scaled by QSCALE). Output attn: [B,S,D] bf16.
// Block: 4 waves x 32 q rows = 128 q rows/block. KV tile = 64, double-buffered.
// K-frag and V-frag LDS reads amortized over 2 q-subtiles per wave.
__global__ __launch_bounds__(256) void attn_kernel(
    const u16* __restrict__ Q, const u16* __restrict__ K,
    const u16* __restrict__ V, u16* __restrict__ attn) {
  __shared__ u16 Kf[2][4096];
  __shared__ u16 Vf[2][4096];
  __shared__ u16 Pf[4][2048];   // per wave: [qsub][1024]

  const int t = threadIdx.x;
  const int lane = t & 63, w = t >> 6;
  const int g = lane >> 4, c = lane & 15;
  const int b = blockIdx.z, h = blockIdx.y, q0 = blockIdx.x * 128;

  const u16* Qh = Q + ((size_t)(b * 16 + h) * 2048) * 64;
  const u16* Kh = K + ((size_t)(b * 16 + h) * 2048) * 64;
  const u16* Vh = V + ((size_t)(b * 16 + h) * 2048) * 64;

  const int qw = q0 + w * 32;
  // Q B-frags for 2 q-subtiles, held in registers for the whole kernel
  bf16x8 qf[2][2];
#pragma unroll
  for (int qs = 0; qs < 2; ++qs) {
    qf[qs][0] = ldfrag(Qh + (size_t)(qw + 16 * qs + c) * 64 + 8 * g);
    qf[qs][1] = ldfrag(Qh + (size_t)(qw + 16 * qs + c) * 64 + 32 + 8 * g);
  }

  const int rv = t >> 3;            // V stage: kv row 0..31 (and +32)
  const int seg = (t & 7) * 8;      // V stage: d segment

  // loop-invariant swizzled V-write offsets (u16 units)
  int vwoff[2][8];
#pragma unroll
  for (int it = 0; it < 2; ++it) {
    int r = rv + 32 * it;
    int m = r >> 5, gg = (r >> 3) & 3, e = r & 7;
#pragma unroll
    for (int l = 0; l < 8; ++l) {
      int d = seg + l;
      int L = ((m * 4 + (d >> 4)) * 4 + gg) * 16 + (d & 15);
      vwoff[it][l] = vswz(L) * 8 + e;
    }
  }

  f32x4 o[2][4] = {};
  float mrow[2] = {-3e38f, -3e38f}, lrow[2] = {0.f, 0.f};

  // ---- prologue: stage tile 0 ----
  {
#pragma unroll
    for (int i = 0; i < 2; ++i) {
      int unit = ((w * 2 + i) << 6) | lane;
      int cc = unit & 15, gg = (unit >> 4) & 3, uu = (unit >> 6) & 1, t4 = (unit >> 7) & 3;
      gll16(Kh + (size_t)(16 * t4 + cc) * 64 + 32 * uu + 8 * gg, &Kf[0][unit * 8]);
    }
    u16x8 v0 = *(const u16x8*)(Vh + (size_t)rv * 64 + seg);
    u16x8 v1 = *(const u16x8*)(Vh + (size_t)(rv + 32) * 64 + seg);
#pragma unroll
    for (int l = 0; l < 8; ++l) Vf[0][vwoff[0][l]] = v0[l];
#pragma unroll
    for (int l = 0; l < 8; ++l) Vf[0][vwoff[1][l]] = v1[l];
    __syncthreads();
  }

  int cur = 0;
  for (int kv0 = 0; kv0 < 2048; kv0 += 64) {
    const int nxt = kv0 + 64;
    const bool pfch = nxt < 2048;
    u16x8 v0, v1;
    if (pfch) {
      // T14: issue next-tile global loads early; ds_writes after compute
      v0 = *(const u16x8*)(Vh + (size_t)(nxt + rv) * 64 + seg);
      v1 = *(const u16x8*)(Vh + (size_t)(nxt + rv + 32) * 64 + seg);
#pragma unroll
      for (int i = 0; i < 2; ++i) {
        int unit = ((w * 2 + i) << 6) | lane;
        int cc = unit & 15, gg = (unit >> 4) & 3, uu = (unit >> 6) & 1, t4 = (unit >> 7) & 3;
        gll16(Kh + (size_t)(nxt + 16 * t4 + cc) * 64 + 32 * uu + 8 * gg,
              &Kf[cur ^ 1][unit * 8]);
      }
    }

    // ---- swapped QK^T: st[t4][qs] = K(16 kv) . Q^T -> S^T[kv][q], q = 16*qs + c ----
    f32x4 st[4][2];
#pragma unroll
    for (int t4 = 0; t4 < 4; ++t4) {
      bf16x8 k0 = ldfrag(&Kf[cur][((t4 * 2 + 0) * 4 + g) * 128 + c * 8]);
      bf16x8 k1 = ldfrag(&Kf[cur][((t4 * 2 + 1) * 4 + g) * 128 + c * 8]);
#pragma unroll
      for (int qs = 0; qs < 2; ++qs) {
        f32x4 acc = {};
        acc = __builtin_amdgcn_mfma_f32_16x16x32_bf16(k0, qf[qs][0], acc, 0, 0, 0);
        st[t4][qs] = __builtin_amdgcn_mfma_f32_16x16x32_bf16(k1, qf[qs][1], acc, 0, 0, 0);
      }
    }

    // ---- online softmax per q-subtile (scores already in log2 units) ----
#pragma unroll
    for (int qs = 0; qs < 2; ++qs) {
      float tmq[4];
#pragma unroll
      for (int t4 = 0; t4 < 4; ++t4)
        tmq[t4] = fmaxf(fmaxf(st[t4][qs][0], st[t4][qs][1]),
                        fmaxf(st[t4][qs][2], st[t4][qs][3]));
      float tm = fmaxf(fmaxf(tmq[0], tmq[1]), fmaxf(tmq[2], tmq[3]));
      tm = fmaxf(tm, __shfl_xor(tm, 16));
      tm = fmaxf(tm, __shfl_xor(tm, 32));
      // T13 defer-max: only rescale when the max grew by >8 (log2 units; P <= 2^8)
      const bool grow = __any(tm > mrow[qs] + 8.0f);
      float nm = grow ? fmaxf(mrow[qs], tm) : mrow[qs];
      float tsq[4];
#pragma unroll
      for (int t4 = 0; t4 < 4; ++t4) {
#pragma unroll
        for (int r = 0; r < 4; ++r) st[t4][qs][r] = exp2f(st[t4][qs][r] - nm);
        tsq[t4] = (st[t4][qs][0] + st[t4][qs][1]) + (st[t4][qs][2] + st[t4][qs][3]);
      }
      float ts = (tsq[0] + tsq[1]) + (tsq[2] + tsq[3]);
      ts += __shfl_xor(ts, 16);
      ts += __shfl_xor(ts, 32);
      if (grow) {
        float f = exp2f(mrow[qs] - nm);
        lrow[qs] = lrow[qs] * f + ts;
        mrow[qs] = nm;
#pragma unroll
        for (int r = 0; r < 4; ++r) {
          float fr = __shfl(f, 4 * g + r);   // f lives at lanes indexed by q=c
#pragma unroll
          for (int j = 0; j < 4; ++j) o[qs][j][r] *= fr;
        }
      } else {
        lrow[qs] += ts;
      }

      // ---- pack P into per-wave A-frag layout (no barrier: same-wave RAW) ----
      u32* pd = (u32*)&Pf[w][qs * 1024];
#pragma unroll
      for (int t4 = 0; t4 < 4; ++t4) {
        u32 w0 = cvt_pk_bf16(st[t4][qs][0], st[t4][qs][1]);
        u32 w1 = cvt_pk_bf16(st[t4][qs][2], st[t4][qs][3]);
        int m = t4 >> 1, gp = (2 * t4 + (g >> 1)) & 3;
        int base = ((m * 4 + gp) * 16 + c) * 4 + 2 * (g & 1);
        pd[base] = w0;
        pd[base + 1] = w1;
      }
    }

    // ---- PV: O[q][d] += P . V (vb frags shared across both q-subtiles) ----
#pragma unroll
    for (int m = 0; m < 2; ++m) {
      bf16x8 vb[4];
#pragma unroll
      for (int j = 0; j < 4; ++j)
        vb[j] = ldfrag(&Vf[cur][vswz(((m * 4 + j) * 4 + g) * 16 + c) * 8]);
#pragma unroll
      for (int qs = 0; qs < 2; ++qs) {
        bf16x8 pa = ldfrag(&Pf[w][qs * 1024 + ((m * 4 + g) * 16 + c) * 8]);
#pragma unroll
        for (int j = 0; j < 4; ++j)
          o[qs][j] = __builtin_amdgcn_mfma_f32_16x16x32_bf16(pa, vb[j], o[qs][j], 0, 0, 0);
      }
    }

    if (pfch) {
#pragma unroll
      for (int l = 0; l < 8; ++l) Vf[cur ^ 1][vwoff[0][l]] = v0[l];
#pragma unroll
      for (int l = 0; l < 8; ++l) Vf[cur ^ 1][vwoff[1][l]] = v1[l];
    }
    __syncthreads();
    cur ^= 1;
  }

  // ---- epilogue: normalize, write attn[B,S,D] (O lane layout: q=16qs+4g+r, d=16j+c) ----
#pragma unroll
  for (int qs = 0; qs < 2; ++qs) {
    float rinv[4];
#pragma unroll
    for (int r = 0; r < 4; ++r) rinv[r] = 1.f / __shfl(lrow[qs], 4 * g + r);
#pragma unroll
    for (int j = 0; j < 4; ++j)
#pragma unroll
      for (int r = 0; r < 4; ++r) {
        int s = qw + 16 * qs + 4 * g + r;
        attn[(size_t)(b * 2048 + s) * 1024 + h * 64 + 16 * j + c] =
            f2bf(o[qs][j][r] * rinv[r]);
      }
  }
}

extern "C" void kernel_launch(void* const* d_in, const int* in_sizes, int n_in,
                              void* d_out, int out_size, void* d_ws, size_t ws_size,
                              hipStream_t stream) {
  const float* x  = (const float*)d_in[0];
  const float* Wq = (const float*)d_in[1];
  const float* bq = (const float*)d_in[2];
  const float* Wk = (const float*)d_in[3];
  const float* bk = (const float*)d_in[4];
  const float* Wv = (const float*)d_in[5];
  const float* bv = (const float*)d_in[6];
  const float* Wo = (const float*)d_in[7];
  const float* bo = (const float*)d_in[8];
  float* out = (float*)d_out;
  u16* ws = (u16*)d_ws;

  // workspace layout (u16 elems): xb 4M | WT 4x1M | Q 4M | K 4M | V 4M  => 40 MB
  u16* xb    = ws;
  u16* WT    = ws + (size_t)4 * 1024 * 1024;
  u16* Qb    = ws + (size_t)8 * 1024 * 1024;
  u16* Kb    = ws + (size_t)12 * 1024 * 1024;
  u16* Vb    = ws + (size_t)16 * 1024 * 1024;
  u16* attnb = xb;  // xb dead after QKV GEMM; reuse for attn output

  cast_x_kernel<<<2048, 256, 0, stream>>>(x, xb);
  transpose_w_kernel<<<dim3(16, 16, 4), 256, 0, stream>>>(Wq, Wk, Wv, Wo, WT);
  qkv_gemm_kernel<<<dim3(8, 32, 3), 256, 0, stream>>>(xb, WT, bq, bk, bv, Qb, Kb, Vb);
  attn_kernel<<<dim3(16, 16, 2), 256, 0, stream>>>(Qb, Kb, Vb, attnb);
  oproj_kernel<<<dim3(8, 32), 256, 0, stream>>>(attnb, WT + (size_t)3 * 1024 * 1024, bo, out);
}

// Round 5
// 158.811 us; speedup vs baseline: 1.0288x; 1.0288x over previous
//
#include <hip/hip_runtime.h>
#include <stdint.h>

// B=2, S=2048, D=1024, H=16, HD=64
typedef unsigned short u16;
typedef unsigned int u32;
typedef __bf16 bf16x8 __attribute__((ext_vector_type(8)));
typedef float f32x4 __attribute__((ext_vector_type(4)));
typedef unsigned short u16x8 __attribute__((ext_vector_type(8)));
typedef unsigned short u16x4 __attribute__((ext_vector_type(4)));

#define QSCALE 0.1803368801111204f  // 0.125 * log2(e): folded into Wq/bq so softmax uses exp2

static __device__ __forceinline__ u16 f2bf(float f) {
  unsigned u = __builtin_bit_cast(unsigned, f);
  u += 0x7fffu + ((u >> 16) & 1u);   // RNE
  return (u16)(u >> 16);
}

static __device__ __forceinline__ bf16x8 ldfrag(const u16* p) {
  return *reinterpret_cast<const bf16x8*>(p);
}

static __device__ __forceinline__ void gll16(const u16* g, u16* l) {
  __builtin_amdgcn_global_load_lds(
      (const __attribute__((address_space(1))) void*)g,
      (__attribute__((address_space(3))) void*)l, 16, 0, 0);
}

static __device__ __forceinline__ u32 cvt_pk_bf16(float lo, float hi) {
  u32 r;
  asm("v_cvt_pk_bf16_f32 %0, %1, %2" : "=v"(r) : "v"(lo), "v"(hi));
  return r;
}

// V-frag LDS swizzle: XOR bits {3,6,7} of the 16B-unit index into bits {0,2:1}.
// Involution; write-side spreads the 8-way-conflicting slots across all 32 banks,
// read-side stays a permutation of each wave's contiguous 1KB (conflict-free).
static __device__ __forceinline__ int vswz(int L) {
  return L ^ ((((L >> 6) & 3) << 1) | ((L >> 3) & 1));
}

// ---------------- cast x: fp32 -> bf16, [4096][1024] ----------------
__global__ __launch_bounds__(256) void cast_x_kernel(const float* __restrict__ x,
                                                     u16* __restrict__ xb) {
  int i = (blockIdx.x * 256 + threadIdx.x) * 8;
  const float4* p = reinterpret_cast<const float4*>(x + i);
  float4 a = p[0], b = p[1];
  u16x8 o;
  o[0] = f2bf(a.x); o[1] = f2bf(a.y); o[2] = f2bf(a.z); o[3] = f2bf(a.w);
  o[4] = f2bf(b.x); o[5] = f2bf(b.y); o[6] = f2bf(b.z); o[7] = f2bf(b.w);
  *reinterpret_cast<u16x8*>(xb + i) = o;
}

// -------- transpose + cast W [k][n] fp32 -> Wt [n][k] bf16 (z picks Wq/Wk/Wv/Wo) --------
__global__ __launch_bounds__(256) void transpose_w_kernel(
    const float* __restrict__ Wq, const float* __restrict__ Wk,
    const float* __restrict__ Wv, const float* __restrict__ Wo,
    u16* __restrict__ WT) {
  __shared__ float tile[64][65];
  int z = blockIdx.z;
  const float* W = (z == 0) ? Wq : (z == 1) ? Wk : (z == 2) ? Wv : Wo;
  float wscale = (z == 0) ? QSCALE : 1.0f;
  u16* out = WT + (size_t)z * 1024 * 1024;
  int k0 = blockIdx.y * 64, n0 = blockIdx.x * 64;
  int t = threadIdx.x;
  int rr = t >> 4;         // 0..15
  int cc = (t & 15) * 4;   // 0..60
#pragma unroll
  for (int j = 0; j < 4; ++j) {
    int r = rr + 16 * j;
    float4 v = *reinterpret_cast<const float4*>(W + (size_t)(k0 + r) * 1024 + n0 + cc);
    tile[r][cc + 0] = v.x; tile[r][cc + 1] = v.y;
    tile[r][cc + 2] = v.z; tile[r][cc + 3] = v.w;
  }
  __syncthreads();
#pragma unroll
  for (int j = 0; j < 4; ++j) {
    int nl = rr + 16 * j;
    u16x4 o;
#pragma unroll
    for (int i2 = 0; i2 < 4; ++i2) o[i2] = f2bf(tile[cc + i2][nl] * wscale);
    *reinterpret_cast<u16x4*>(out + (size_t)(n0 + nl) * 1024 + k0 + cc) = o;
  }
}

// ---------------- generic bf16 GEMM: C[4096][1024] = A @ Wt^T + bias ----------------
template <int MODE>
static __device__ __forceinline__ void gemm_body(const u16* __restrict__ A,
                                                 const u16* __restrict__ Wt,
                                                 const float* __restrict__ bias,
                                                 float bscale,
                                                 void* __restrict__ Out) {
  __shared__ u16 As[128 * 32];
  __shared__ u16 Bs[128 * 32];
  int t = threadIdx.x;
  int lane = t & 63, wave = t >> 6;
  int g = lane >> 4, c = lane & 15;
  int m0 = blockIdx.y * 128, n0 = blockIdx.x * 128;
  int wm = (wave >> 1) * 64, wn = (wave & 1) * 64;

  f32x4 acc[4][4] = {};

  const u16* Ag = A + (size_t)(m0 + (t >> 2)) * 1024 + (t & 3) * 8;
  const u16* Bg = Wt + (size_t)(n0 + (t >> 2)) * 1024 + (t & 3) * 8;
  u16* Asd = As + t * 8;
  u16* Bsd = Bs + t * 8;

  for (int k0 = 0; k0 < 1024; k0 += 32) {
    gll16(Ag + k0, Asd);
    gll16(Ag + 64 * 1024 + k0, Asd + 64 * 32);
    gll16(Bg + k0, Bsd);
    gll16(Bg + 64 * 1024 + k0, Bsd + 64 * 32);
    __syncthreads();
    bf16x8 af[4], bfr[4];
#pragma unroll
    for (int i = 0; i < 4; ++i) {
      af[i]  = ldfrag(As + (wm + 16 * i + c) * 32 + g * 8);
      bfr[i] = ldfrag(Bs + (wn + 16 * i + c) * 32 + g * 8);
    }
#pragma unroll
    for (int i = 0; i < 4; ++i)
#pragma unroll
      for (int j = 0; j < 4; ++j)
        acc[i][j] = __builtin_amdgcn_mfma_f32_16x16x32_bf16(af[i], bfr[j], acc[i][j], 0, 0, 0);
    __syncthreads();
  }

  if (MODE == 0) {
    u16* out = (u16*)Out;
#pragma unroll
    for (int i = 0; i < 4; ++i) {
      int mb = m0 + wm + 16 * i + g * 4;
#pragma unroll
      for (int j = 0; j < 4; ++j) {
        int n = n0 + wn + 16 * j + c;
        float bv = bias[n] * bscale;
        int h = n >> 6, d = n & 63;
#pragma unroll
        for (int r = 0; r < 4; ++r) {
          int m = mb + r;
          int b = m >> 11, s = m & 2047;   // m = b*2048 + s
          out[((size_t)(b * 16 + h) * 2048 + s) * 64 + d] = f2bf(acc[i][j][r] + bv);
        }
      }
    }
  } else {
    float* out = (float*)Out;
#pragma unroll
    for (int i = 0; i < 4; ++i) {
      int mb = m0 + wm + 16 * i + g * 4;
#pragma unroll
      for (int j = 0; j < 4; ++j) {
        int n = n0 + wn + 16 * j + c;
        float bv = bias[n];
#pragma unroll
        for (int r = 0; r < 4; ++r)
          out[(size_t)(mb + r) * 1024 + n] = acc[i][j][r] + bv;
      }
    }
  }
}

__global__ __launch_bounds__(256) void qkv_gemm_kernel(
    const u16* __restrict__ xb, const u16* __restrict__ WT,
    const float* __restrict__ bq, const float* __restrict__ bk,
    const float* __restrict__ bv,
    u16* __restrict__ Q, u16* __restrict__ K, u16* __restrict__ V) {
  int z = blockIdx.z;
  const u16* Wt = WT + (size_t)z * 1024 * 1024;
  const float* bias = (z == 0) ? bq : (z == 1) ? bk : bv;
  float bscale = (z == 0) ? QSCALE : 1.0f;
  u16* out = (z == 0) ? Q : (z == 1) ? K : V;
  gemm_body<0>(xb, Wt, bias, bscale, out);
}

__global__ __launch_bounds__(256) void oproj_kernel(
    const u16* __restrict__ attnb, const u16* __restrict__ WoT,
    const float* __restrict__ bo, float* __restrict__ out) {
  gemm_body<1>(attnb, WoT, bo, 1.0f, out);
}

// ---------------- flash attention (swapped-QK, frag-native LDS, KVBLK=64) ----------------
// Q,K,V: [B,H,S,HD] bf16 (Q pre-scaled by QSCALE). Output attn: [B,S,D] bf16.
// Block: 4 waves x 16 q rows. KV tile = 64, double-buffered. LDS = 36 KB -> 4 blocks/CU.
__global__ __launch_bounds__(256) void attn_kernel(
    const u16* __restrict__ Q, const u16* __restrict__ K,
    const u16* __restrict__ V, u16* __restrict__ attn) {
  __shared__ u16 Kf[2][4096];
  __shared__ u16 Vf[2][4096];
  __shared__ u16 Pf[4][512];   // per-wave 1KB: 16q x 32kv bf16 (reused across m-halves)

  const int t = threadIdx.x;
  const int lane = t & 63, w = t >> 6;
  const int g = lane >> 4, c = lane & 15;
  const int b = blockIdx.z, h = blockIdx.y, q0 = blockIdx.x * 64;

  const u16* Qh = Q + ((size_t)(b * 16 + h) * 2048) * 64;
  const u16* Kh = K + ((size_t)(b * 16 + h) * 2048) * 64;
  const u16* Vh = V + ((size_t)(b * 16 + h) * 2048) * 64;

  const int qw = q0 + w * 16;
  // Q B-frags, held in registers for the whole kernel
  bf16x8 qf0 = ldfrag(Qh + (size_t)(qw + c) * 64 + 8 * g);
  bf16x8 qf1 = ldfrag(Qh + (size_t)(qw + c) * 64 + 32 + 8 * g);

  const int rv = t >> 3;            // V stage: kv row 0..31 (and +32)
  const int seg = (t & 7) * 8;      // V stage: d segment

  // loop-invariant swizzled V-write offsets (u16 units)
  int vwoff[2][8];
#pragma unroll
  for (int it = 0; it < 2; ++it) {
    int r = rv + 32 * it;
    int m = r >> 5, gg = (r >> 3) & 3, e = r & 7;
#pragma unroll
    for (int l = 0; l < 8; ++l) {
      int d = seg + l;
      int L = ((m * 4 + (d >> 4)) * 4 + gg) * 16 + (d & 15);
      vwoff[it][l] = vswz(L) * 8 + e;
    }
  }

  f32x4 o[4] = {};
  float mrow = -3e38f, lrow = 0.f;

  // ---- prologue: stage tile 0 ----
  {
#pragma unroll
    for (int i = 0; i < 2; ++i) {
      int unit = ((w * 2 + i) << 6) | lane;
      int cc = unit & 15, gg = (unit >> 4) & 3, uu = (unit >> 6) & 1, t4 = (unit >> 7) & 3;
      gll16(Kh + (size_t)(16 * t4 + cc) * 64 + 32 * uu + 8 * gg, &Kf[0][unit * 8]);
    }
    u16x8 v0 = *(const u16x8*)(Vh + (size_t)rv * 64 + seg);
    u16x8 v1 = *(const u16x8*)(Vh + (size_t)(rv + 32) * 64 + seg);
#pragma unroll
    for (int l = 0; l < 8; ++l) Vf[0][vwoff[0][l]] = v0[l];
#pragma unroll
    for (int l = 0; l < 8; ++l) Vf[0][vwoff[1][l]] = v1[l];
    __syncthreads();
  }

  int cur = 0;
  for (int kv0 = 0; kv0 < 2048; kv0 += 64) {
    const int nxt = kv0 + 64;
    const bool pfch = nxt < 2048;
    u16x8 v0, v1;
    if (pfch) {
      // T14: issue next-tile global loads early; ds_writes after compute
      v0 = *(const u16x8*)(Vh + (size_t)(nxt + rv) * 64 + seg);
      v1 = *(const u16x8*)(Vh + (size_t)(nxt + rv + 32) * 64 + seg);
#pragma unroll
      for (int i = 0; i < 2; ++i) {
        int unit = ((w * 2 + i) << 6) | lane;
        int cc = unit & 15, gg = (unit >> 4) & 3, uu = (unit >> 6) & 1, t4 = (unit >> 7) & 3;
        gll16(Kh + (size_t)(nxt + 16 * t4 + cc) * 64 + 32 * uu + 8 * gg,
              &Kf[cur ^ 1][unit * 8]);
      }
    }

    // ---- swapped QK^T: st[t4] = K(16 kv) . Q^T -> S^T[kv][q], q = c per lane ----
    f32x4 st[4];
    __builtin_amdgcn_s_setprio(1);
#pragma unroll
    for (int t4 = 0; t4 < 4; ++t4) {
      f32x4 acc = {};
      acc = __builtin_amdgcn_mfma_f32_16x16x32_bf16(
          ldfrag(&Kf[cur][((t4 * 2 + 0) * 4 + g) * 128 + c * 8]), qf0, acc, 0, 0, 0);
      st[t4] = __builtin_amdgcn_mfma_f32_16x16x32_bf16(
          ldfrag(&Kf[cur][((t4 * 2 + 1) * 4 + g) * 128 + c * 8]), qf1, acc, 0, 0, 0);
    }
    __builtin_amdgcn_s_setprio(0);

    // ---- online softmax over 64-kv tile (scores already in log2 units) ----
    float tmq[4];
#pragma unroll
    for (int t4 = 0; t4 < 4; ++t4)
      tmq[t4] = fmaxf(fmaxf(st[t4][0], st[t4][1]), fmaxf(st[t4][2], st[t4][3]));
    float tm = fmaxf(fmaxf(tmq[0], tmq[1]), fmaxf(tmq[2], tmq[3]));
    tm = fmaxf(tm, __shfl_xor(tm, 16));
    tm = fmaxf(tm, __shfl_xor(tm, 32));
    // T13 defer-max: only rescale when the max grew by >8 (log2 units; P <= 2^8)
    const bool grow = __any(tm > mrow + 8.0f);
    float nm = grow ? fmaxf(mrow, tm) : mrow;
    float tsq[4];
#pragma unroll
    for (int t4 = 0; t4 < 4; ++t4) {
#pragma unroll
      for (int r = 0; r < 4; ++r) st[t4][r] = exp2f(st[t4][r] - nm);
      tsq[t4] = (st[t4][0] + st[t4][1]) + (st[t4][2] + st[t4][3]);
    }
    float ts = (tsq[0] + tsq[1]) + (tsq[2] + tsq[3]);
    ts += __shfl_xor(ts, 16);
    ts += __shfl_xor(ts, 32);
    if (grow) {
      float f = exp2f(mrow - nm);
      lrow = lrow * f + ts;
      mrow = nm;
#pragma unroll
      for (int r = 0; r < 4; ++r) {
        float fr = __shfl(f, 4 * g + r);   // f lives at lanes indexed by q=c
#pragma unroll
        for (int j = 0; j < 4; ++j) o[j][r] *= fr;
      }
    } else {
      lrow += ts;
    }

    // ---- pack P (per 32-kv half) into per-wave A-frag layout, then PV on that half ----
    // Same-wave DS ordering makes the 1KB Pf reusable across m-halves (no barrier).
    u32* pd = (u32*)&Pf[w][0];
#pragma unroll
    for (int m = 0; m < 2; ++m) {
#pragma unroll
      for (int tt = 0; tt < 2; ++tt) {
        int t4 = 2 * m + tt;
        u32 w0 = cvt_pk_bf16(st[t4][0], st[t4][1]);
        u32 w1 = cvt_pk_bf16(st[t4][2], st[t4][3]);
        int gp = (2 * t4 + (g >> 1)) & 3;
        int base = (gp * 16 + c) * 4 + 2 * (g & 1);
        pd[base] = w0;
        pd[base + 1] = w1;
      }
      bf16x8 pa = ldfrag(&Pf[w][(g * 16 + c) * 8]);
      __builtin_amdgcn_s_setprio(1);
#pragma unroll
      for (int j = 0; j < 4; ++j) {
        bf16x8 vb = ldfrag(&Vf[cur][vswz(((m * 4 + j) * 4 + g) * 16 + c) * 8]);
        o[j] = __builtin_amdgcn_mfma_f32_16x16x32_bf16(pa, vb, o[j], 0, 0, 0);
      }
      __builtin_amdgcn_s_setprio(0);
    }

    if (pfch) {
#pragma unroll
      for (int l = 0; l < 8; ++l) Vf[cur ^ 1][vwoff[0][l]] = v0[l];
#pragma unroll
      for (int l = 0; l < 8; ++l) Vf[cur ^ 1][vwoff[1][l]] = v1[l];
    }
    __syncthreads();
    cur ^= 1;
  }

  // ---- epilogue: normalize, write attn[B,S,D] (O lane layout: q=4g+r, d=16j+c) ----
  float rinv[4];
#pragma unroll
  for (int r = 0; r < 4; ++r) rinv[r] = 1.f / __shfl(lrow, 4 * g + r);
#pragma unroll
  for (int j = 0; j < 4; ++j)
#pragma unroll
    for (int r = 0; r < 4; ++r) {
      int s = qw + 4 * g + r;
      attn[(size_t)(b * 2048 + s) * 1024 + h * 64 + 16 * j + c] = f2bf(o[j][r] * rinv[r]);
    }
}

extern "C" void kernel_launch(void* const* d_in, const int* in_sizes, int n_in,
                              void* d_out, int out_size, void* d_ws, size_t ws_size,
                              hipStream_t stream) {
  const float* x  = (const float*)d_in[0];
  const float* Wq = (const float*)d_in[1];
  const float* bq = (const float*)d_in[2];
  const float* Wk = (const float*)d_in[3];
  const float* bk = (const float*)d_in[4];
  const float* Wv = (const float*)d_in[5];
  const float* bv = (const float*)d_in[6];
  const float* Wo = (const float*)d_in[7];
  const float* bo = (const float*)d_in[8];
  float* out = (float*)d_out;
  u16* ws = (u16*)d_ws;

  // workspace layout (u16 elems): xb 4M | WT 4x1M | Q 4M | K 4M | V 4M  => 40 MB
  u16* xb    = ws;
  u16* WT    = ws + (size_t)4 * 1024 * 1024;
  u16* Qb    = ws + (size_t)8 * 1024 * 1024;
  u16* Kb    = ws + (size_t)12 * 1024 * 1024;
  u16* Vb    = ws + (size_t)16 * 1024 * 1024;
  u16* attnb = xb;  // xb dead after QKV GEMM; reuse for attn output

  cast_x_kernel<<<2048, 256, 0, stream>>>(x, xb);
  transpose_w_kernel<<<dim3(16, 16, 4), 256, 0, stream>>>(Wq, Wk, Wv, Wo, WT);
  qkv_gemm_kernel<<<dim3(8, 32, 3), 256, 0, stream>>>(xb, WT, bq, bk, bv, Qb, Kb, Vb);
  attn_kernel<<<dim3(32, 16, 2), 256, 0, stream>>>(Qb, Kb, Vb, attnb);
  oproj_kernel<<<dim3(8, 32), 256, 0, stream>>>(attnb, WT + (size_t)3 * 1024 * 1024, bo, out);
}

// Round 6
// 158.429 us; speedup vs baseline: 1.0313x; 1.0024x over previous
//
#include <hip/hip_runtime.h>
#include <stdint.h>

// B=2, S=2048, D=1024, H=16, HD=64
typedef unsigned short u16;
typedef unsigned int u32;
typedef unsigned long long u64;
typedef __bf16 bf16x8 __attribute__((ext_vector_type(8)));
typedef float f32x4 __attribute__((ext_vector_type(4)));
typedef unsigned short u16x8 __attribute__((ext_vector_type(8)));
typedef unsigned short u16x4 __attribute__((ext_vector_type(4)));

#define QSCALE 0.1803368801111204f  // 0.125 * log2(e): folded into Wq/bq so softmax uses exp2

static __device__ __forceinline__ u16 f2bf(float f) {
  unsigned u = __builtin_bit_cast(unsigned, f);
  u += 0x7fffu + ((u >> 16) & 1u);   // RNE
  return (u16)(u >> 16);
}

static __device__ __forceinline__ bf16x8 ldfrag(const u16* p) {
  return *reinterpret_cast<const bf16x8*>(p);
}

static __device__ __forceinline__ void gll16(const u16* g, u16* l) {
  __builtin_amdgcn_global_load_lds(
      (const __attribute__((address_space(1))) void*)g,
      (__attribute__((address_space(3))) void*)l, 16, 0, 0);
}

static __device__ __forceinline__ u32 cvt_pk_bf16(float lo, float hi) {
  u32 r;
  asm("v_cvt_pk_bf16_f32 %0, %1, %2" : "=v"(r) : "v"(lo), "v"(hi));
  return r;
}

// raw v_exp_f32 (2^x): avoids the non-fast-math denormal-guard expansion of exp2f.
static __device__ __forceinline__ float fexp2(float x) {
  return __builtin_amdgcn_exp2f(x);
}

// ---------------- cast x: fp32 -> bf16, [4096][1024] ----------------
__global__ __launch_bounds__(256) void cast_x_kernel(const float* __restrict__ x,
                                                     u16* __restrict__ xb) {
  int i = (blockIdx.x * 256 + threadIdx.x) * 8;
  const float4* p = reinterpret_cast<const float4*>(x + i);
  float4 a = p[0], b = p[1];
  u16x8 o;
  o[0] = f2bf(a.x); o[1] = f2bf(a.y); o[2] = f2bf(a.z); o[3] = f2bf(a.w);
  o[4] = f2bf(b.x); o[5] = f2bf(b.y); o[6] = f2bf(b.z); o[7] = f2bf(b.w);
  *reinterpret_cast<u16x8*>(xb + i) = o;
}

// -------- transpose + cast W [k][n] fp32 -> Wt [n][k] bf16 (z picks Wq/Wk/Wv/Wo) --------
__global__ __launch_bounds__(256) void transpose_w_kernel(
    const float* __restrict__ Wq, const float* __restrict__ Wk,
    const float* __restrict__ Wv, const float* __restrict__ Wo,
    u16* __restrict__ WT) {
  __shared__ float tile[64][65];
  int z = blockIdx.z;
  const float* W = (z == 0) ? Wq : (z == 1) ? Wk : (z == 2) ? Wv : Wo;
  float wscale = (z == 0) ? QSCALE : 1.0f;
  u16* out = WT + (size_t)z * 1024 * 1024;
  int k0 = blockIdx.y * 64, n0 = blockIdx.x * 64;
  int t = threadIdx.x;
  int rr = t >> 4;         // 0..15
  int cc = (t & 15) * 4;   // 0..60
#pragma unroll
  for (int j = 0; j < 4; ++j) {
    int r = rr + 16 * j;
    float4 v = *reinterpret_cast<const float4*>(W + (size_t)(k0 + r) * 1024 + n0 + cc);
    tile[r][cc + 0] = v.x; tile[r][cc + 1] = v.y;
    tile[r][cc + 2] = v.z; tile[r][cc + 3] = v.w;
  }
  __syncthreads();
#pragma unroll
  for (int j = 0; j < 4; ++j) {
    int nl = rr + 16 * j;
    u16x4 o;
#pragma unroll
    for (int i2 = 0; i2 < 4; ++i2) o[i2] = f2bf(tile[cc + i2][nl] * wscale);
    *reinterpret_cast<u16x4*>(out + (size_t)(n0 + nl) * 1024 + k0 + cc) = o;
  }
}

// ---------------- generic bf16 GEMM: C[4096][1024] = A @ Wt^T + bias ----------------
// MODE 0: bf16 out to [B,H,S,HD].  MODE 1: fp32 linear [m][n].  MODE 2: bf16 out TRANSPOSED
// to [B,H,HD,S] (for V: makes attention's PV B-operand a row-contiguous read).
template <int MODE>
static __device__ __forceinline__ void gemm_body(const u16* __restrict__ A,
                                                 const u16* __restrict__ Wt,
                                                 const float* __restrict__ bias,
                                                 float bscale,
                                                 void* __restrict__ Out) {
  __shared__ u16 As[128 * 32];
  __shared__ u16 Bs[128 * 32];
  int t = threadIdx.x;
  int lane = t & 63, wave = t >> 6;
  int g = lane >> 4, c = lane & 15;
  int m0 = blockIdx.y * 128, n0 = blockIdx.x * 128;
  int wm = (wave >> 1) * 64, wn = (wave & 1) * 64;

  f32x4 acc[4][4] = {};

  const u16* Ag = A + (size_t)(m0 + (t >> 2)) * 1024 + (t & 3) * 8;
  const u16* Bg = Wt + (size_t)(n0 + (t >> 2)) * 1024 + (t & 3) * 8;
  u16* Asd = As + t * 8;
  u16* Bsd = Bs + t * 8;

  for (int k0 = 0; k0 < 1024; k0 += 32) {
    gll16(Ag + k0, Asd);
    gll16(Ag + 64 * 1024 + k0, Asd + 64 * 32);
    gll16(Bg + k0, Bsd);
    gll16(Bg + 64 * 1024 + k0, Bsd + 64 * 32);
    __syncthreads();
    bf16x8 af[4], bfr[4];
#pragma unroll
    for (int i = 0; i < 4; ++i) {
      af[i]  = ldfrag(As + (wm + 16 * i + c) * 32 + g * 8);
      bfr[i] = ldfrag(Bs + (wn + 16 * i + c) * 32 + g * 8);
    }
#pragma unroll
    for (int i = 0; i < 4; ++i)
#pragma unroll
      for (int j = 0; j < 4; ++j)
        acc[i][j] = __builtin_amdgcn_mfma_f32_16x16x32_bf16(af[i], bfr[j], acc[i][j], 0, 0, 0);
    __syncthreads();
  }

  if (MODE == 0) {
    u16* out = (u16*)Out;
#pragma unroll
    for (int i = 0; i < 4; ++i) {
      int mb = m0 + wm + 16 * i + g * 4;
#pragma unroll
      for (int j = 0; j < 4; ++j) {
        int n = n0 + wn + 16 * j + c;
        float bv = bias[n] * bscale;
        int h = n >> 6, d = n & 63;
#pragma unroll
        for (int r = 0; r < 4; ++r) {
          int m = mb + r;
          int b = m >> 11, s = m & 2047;   // m = b*2048 + s
          out[((size_t)(b * 16 + h) * 2048 + s) * 64 + d] = f2bf(acc[i][j][r] + bv);
        }
      }
    }
  } else if (MODE == 2) {
    u16* out = (u16*)Out;
#pragma unroll
    for (int i = 0; i < 4; ++i) {
      int mb = m0 + wm + 16 * i + g * 4;
      int b = mb >> 11, s0 = mb & 2047;    // 4 consecutive tokens share b
#pragma unroll
      for (int j = 0; j < 4; ++j) {
        int n = n0 + wn + 16 * j + c;
        float bv = bias[n];
        int h = n >> 6, d = n & 63;
        u16x4 o4;
#pragma unroll
        for (int r = 0; r < 4; ++r) o4[r] = f2bf(acc[i][j][r] + bv);
        *reinterpret_cast<u16x4*>(
            out + ((size_t)(b * 16 + h) * 64 + d) * 2048 + s0) = o4;
      }
    }
  } else {
    float* out = (float*)Out;
#pragma unroll
    for (int i = 0; i < 4; ++i) {
      int mb = m0 + wm + 16 * i + g * 4;
#pragma unroll
      for (int j = 0; j < 4; ++j) {
        int n = n0 + wn + 16 * j + c;
        float bv = bias[n];
#pragma unroll
        for (int r = 0; r < 4; ++r)
          out[(size_t)(mb + r) * 1024 + n] = acc[i][j][r] + bv;
      }
    }
  }
}

__global__ __launch_bounds__(256) void qkv_gemm_kernel(
    const u16* __restrict__ xb, const u16* __restrict__ WT,
    const float* __restrict__ bq, const float* __restrict__ bk,
    const float* __restrict__ bv,
    u16* __restrict__ Q, u16* __restrict__ K, u16* __restrict__ V) {
  int z = blockIdx.z;
  const u16* Wt = WT + (size_t)z * 1024 * 1024;
  if (z == 0)      gemm_body<0>(xb, Wt, bq, QSCALE, Q);
  else if (z == 1) gemm_body<0>(xb, Wt, bk, 1.0f, K);
  else             gemm_body<2>(xb, Wt, bv, 1.0f, V);   // V stored transposed [B,H,HD,S]
}

__global__ __launch_bounds__(256) void oproj_kernel(
    const u16* __restrict__ attnb, const u16* __restrict__ WoT,
    const float* __restrict__ bo, float* __restrict__ out) {
  gemm_body<1>(attnb, WoT, bo, 1.0f, out);
}

// ---------------- flash attention (swapped-QK, frag-native LDS, KVBLK=64) ----------------
// Q,K: [B,H,S,HD] bf16 (Q pre-scaled). V: [B,H,HD,S] bf16 (transposed). Out: [B,S,D] bf16.
// Block: 4 waves x 16 q rows. KV tile = 64, double-buffered. LDS = 36 KB.
// V^T tile [64d][64kv] staged entirely by global_load_lds with XOR-swizzled global source:
//   LDS slot (d, sl) holds V^T[d][kv0 + ((sl^(d&7))*8) .. +7]  (sl = 16B slot 0..7)
//   -> PV B-frag = ds_read_b128 at d*64 + ((4m+g)^(d&7))*8; 8 lanes/16B-column = conflict-free.
__global__ __launch_bounds__(256) void attn_kernel(
    const u16* __restrict__ Q, const u16* __restrict__ K,
    const u16* __restrict__ V, u16* __restrict__ attn) {
  __shared__ u16 Kf[2][4096];
  __shared__ u16 Vt[2][4096];
  __shared__ u16 Pf[4][512];   // per-wave 1KB: 16q x 32kv bf16 (reused across m-halves)

  const int t = threadIdx.x;
  const int lane = t & 63, w = t >> 6;
  const int g = lane >> 4, c = lane & 15;
  const int b = blockIdx.z, h = blockIdx.y, q0 = blockIdx.x * 64;

  const u16* Qh = Q + ((size_t)(b * 16 + h) * 2048) * 64;
  const u16* Kh = K + ((size_t)(b * 16 + h) * 2048) * 64;
  const u16* VTh = V + ((size_t)(b * 16 + h) * 64) * 2048;

  const int qw = q0 + w * 16;
  // Q B-frags, held in registers for the whole kernel
  bf16x8 qf0 = ldfrag(Qh + (size_t)(qw + c) * 64 + 8 * g);
  bf16x8 qf1 = ldfrag(Qh + (size_t)(qw + c) * 64 + 32 + 8 * g);

  // per-lane V^T staging source (wave w stages d rows [16w, 16w+16))
  // lane l covers d = 16w + 8i + (l>>3), kv 16B-slot sl = l&7, global kv off (sl^(d&7))*8
  const u16* vsrc = VTh + (size_t)(16 * w + (lane >> 3)) * 2048 +
                    (((lane & 7) ^ ((lane >> 3) & 7)) * 8);
  u16* vdst0 = &Vt[0][16 * w * 64];
  u16* vdst1 = &Vt[1][16 * w * 64];

  f32x4 o[4] = {};
  float mrow = -3e38f, lrow = 0.f;

  // ---- prologue: stage tile 0 ----
  {
#pragma unroll
    for (int i = 0; i < 2; ++i) {
      int unit = ((w * 2 + i) << 6) | lane;
      int cc = unit & 15, gg = (unit >> 4) & 3, uu = (unit >> 6) & 1, t4 = (unit >> 7) & 3;
      gll16(Kh + (size_t)(16 * t4 + cc) * 64 + 32 * uu + 8 * gg, &Kf[0][unit * 8]);
      gll16(vsrc + (size_t)(8 * i) * 2048, vdst0 + i * 512);
    }
    __syncthreads();
  }

  int cur = 0;
  for (int kv0 = 0; kv0 < 2048; kv0 += 64) {
    const int nxt = kv0 + 64;
    const bool pfch = nxt < 2048;
    if (pfch) {
      // prefetch next tile straight to LDS (async; drained by the end-of-loop barrier)
      u16* vdst = cur ? vdst0 : vdst1;
#pragma unroll
      for (int i = 0; i < 2; ++i) {
        int unit = ((w * 2 + i) << 6) | lane;
        int cc = unit & 15, gg = (unit >> 4) & 3, uu = (unit >> 6) & 1, t4 = (unit >> 7) & 3;
        gll16(Kh + (size_t)(nxt + 16 * t4 + cc) * 64 + 32 * uu + 8 * gg,
              &Kf[cur ^ 1][unit * 8]);
        gll16(vsrc + (size_t)(8 * i) * 2048 + nxt, vdst + i * 512);
      }
    }

    // ---- swapped QK^T: st[t4] = K(16 kv) . Q^T -> S^T[kv][q], q = c per lane ----
    f32x4 st[4];
    __builtin_amdgcn_s_setprio(1);
#pragma unroll
    for (int t4 = 0; t4 < 4; ++t4) {
      f32x4 acc = {};
      acc = __builtin_amdgcn_mfma_f32_16x16x32_bf16(
          ldfrag(&Kf[cur][((t4 * 2 + 0) * 4 + g) * 128 + c * 8]), qf0, acc, 0, 0, 0);
      st[t4] = __builtin_amdgcn_mfma_f32_16x16x32_bf16(
          ldfrag(&Kf[cur][((t4 * 2 + 1) * 4 + g) * 128 + c * 8]), qf1, acc, 0, 0, 0);
    }
    __builtin_amdgcn_s_setprio(0);

    // ---- online softmax over 64-kv tile (scores already in log2 units) ----
    float tmq[4];
#pragma unroll
    for (int t4 = 0; t4 < 4; ++t4)
      tmq[t4] = fmaxf(fmaxf(st[t4][0], st[t4][1]), fmaxf(st[t4][2], st[t4][3]));
    float tm = fmaxf(fmaxf(tmq[0], tmq[1]), fmaxf(tmq[2], tmq[3]));
    tm = fmaxf(tm, __shfl_xor(tm, 16));
    tm = fmaxf(tm, __shfl_xor(tm, 32));
    // T13 defer-max: only rescale when the max grew by >8 (log2 units; P <= 2^8)
    const bool grow = __any(tm > mrow + 8.0f);
    float nm = grow ? fmaxf(mrow, tm) : mrow;
    float tsq[4];
#pragma unroll
    for (int t4 = 0; t4 < 4; ++t4) {
#pragma unroll
      for (int r = 0; r < 4; ++r) st[t4][r] = fexp2(st[t4][r] - nm);
      tsq[t4] = (st[t4][0] + st[t4][1]) + (st[t4][2] + st[t4][3]);
    }
    float ts = (tsq[0] + tsq[1]) + (tsq[2] + tsq[3]);
    ts += __shfl_xor(ts, 16);
    ts += __shfl_xor(ts, 32);
    if (grow) {
      float f = fexp2(mrow - nm);
      lrow = lrow * f + ts;
      mrow = nm;
#pragma unroll
      for (int r = 0; r < 4; ++r) {
        float fr = __shfl(f, 4 * g + r);   // f lives at lanes indexed by q=c
#pragma unroll
        for (int j = 0; j < 4; ++j) o[j][r] *= fr;
      }
    } else {
      lrow += ts;
    }

    // ---- pack P (per 32-kv half) into per-wave A-frag layout, then PV on that half ----
    u32* pd = (u32*)&Pf[w][0];
#pragma unroll
    for (int m = 0; m < 2; ++m) {
#pragma unroll
      for (int tt = 0; tt < 2; ++tt) {
        int t4 = 2 * m + tt;
        u32 w0 = cvt_pk_bf16(st[t4][0], st[t4][1]);
        u32 w1 = cvt_pk_bf16(st[t4][2], st[t4][3]);
        int gp = (2 * t4 + (g >> 1)) & 3;
        int base = (gp * 16 + c) * 4 + 2 * (g & 1);
        *reinterpret_cast<u64*>(&pd[base]) = (u64)w0 | ((u64)w1 << 32);
      }
      bf16x8 pa = ldfrag(&Pf[w][(g * 16 + c) * 8]);
      __builtin_amdgcn_s_setprio(1);
#pragma unroll
      for (int j = 0; j < 4; ++j) {
        int d = 16 * j + c;
        bf16x8 vb = ldfrag(&Vt[cur][d * 64 + (((4 * m + g) ^ (d & 7)) * 8)]);
        o[j] = __builtin_amdgcn_mfma_f32_16x16x32_bf16(pa, vb, o[j], 0, 0, 0);
      }
      __builtin_amdgcn_s_setprio(0);
    }

    __syncthreads();
    cur ^= 1;
  }

  // ---- epilogue: normalize, write attn[B,S,D] (O lane layout: q=4g+r, d=16j+c) ----
  float rinv[4];
#pragma unroll
  for (int r = 0; r < 4; ++r) rinv[r] = 1.f / __shfl(lrow, 4 * g + r);
#pragma unroll
  for (int j = 0; j < 4; ++j)
#pragma unroll
    for (int r = 0; r < 4; ++r) {
      int s = qw + 4 * g + r;
      attn[(size_t)(b * 2048 + s) * 1024 + h * 64 + 16 * j + c] = f2bf(o[j][r] * rinv[r]);
    }
}

extern "C" void kernel_launch(void* const* d_in, const int* in_sizes, int n_in,
                              void* d_out, int out_size, void* d_ws, size_t ws_size,
                              hipStream_t stream) {
  const float* x  = (const float*)d_in[0];
  const float* Wq = (const float*)d_in[1];
  const float* bq = (const float*)d_in[2];
  const float* Wk = (const float*)d_in[3];
  const float* bk = (const float*)d_in[4];
  const float* Wv = (const float*)d_in[5];
  const float* bv = (const float*)d_in[6];
  const float* Wo = (const float*)d_in[7];
  const float* bo = (const float*)d_in[8];
  float* out = (float*)d_out;
  u16* ws = (u16*)d_ws;

  // workspace layout (u16 elems): xb 4M | WT 4x1M | Q 4M | K 4M | V^T 4M  => 40 MB
  u16* xb    = ws;
  u16* WT    = ws + (size_t)4 * 1024 * 1024;
  u16* Qb    = ws + (size_t)8 * 1024 * 1024;
  u16* Kb    = ws + (size_t)12 * 1024 * 1024;
  u16* Vb    = ws + (size_t)16 * 1024 * 1024;
  u16* attnb = xb;  // xb dead after QKV GEMM; reuse for attn output

  cast_x_kernel<<<2048, 256, 0, stream>>>(x, xb);
  transpose_w_kernel<<<dim3(16, 16, 4), 256, 0, stream>>>(Wq, Wk, Wv, Wo, WT);
  qkv_gemm_kernel<<<dim3(8, 32, 3), 256, 0, stream>>>(xb, WT, bq, bk, bv, Qb, Kb, Vb);
  attn_kernel<<<dim3(32, 16, 2), 256, 0, stream>>>(Qb, Kb, Vb, attnb);
  oproj_kernel<<<dim3(8, 32), 256, 0, stream>>>(attnb, WT + (size_t)3 * 1024 * 1024, bo, out);
}

// Round 7
// 157.024 us; speedup vs baseline: 1.0405x; 1.0089x over previous
//
#include <hip/hip_runtime.h>
#include <stdint.h>

// B=2, S=2048, D=1024, H=16, HD=64
typedef unsigned short u16;
typedef unsigned int u32;
typedef unsigned long long u64;
typedef __bf16 bf16x8 __attribute__((ext_vector_type(8)));
typedef float f32x4 __attribute__((ext_vector_type(4)));
typedef unsigned short u16x8 __attribute__((ext_vector_type(8)));
typedef unsigned short u16x4 __attribute__((ext_vector_type(4)));

#define QSCALE 0.1803368801111204f  // 0.125 * log2(e): folded into Wq/bq so softmax uses exp2

static __device__ __forceinline__ u16 f2bf(float f) {
  unsigned u = __builtin_bit_cast(unsigned, f);
  u += 0x7fffu + ((u >> 16) & 1u);   // RNE
  return (u16)(u >> 16);
}

static __device__ __forceinline__ bf16x8 ldfrag(const u16* p) {
  return *reinterpret_cast<const bf16x8*>(p);
}

static __device__ __forceinline__ void gll16(const u16* g, u16* l) {
  __builtin_amdgcn_global_load_lds(
      (const __attribute__((address_space(1))) void*)g,
      (__attribute__((address_space(3))) void*)l, 16, 0, 0);
}

static __device__ __forceinline__ u32 cvt_pk_bf16(float lo, float hi) {
  u32 r;
  asm("v_cvt_pk_bf16_f32 %0, %1, %2" : "=v"(r) : "v"(lo), "v"(hi));
  return r;
}

// raw v_exp_f32 (2^x): avoids the non-fast-math denormal-guard expansion of exp2f.
static __device__ __forceinline__ float fexp2(float x) {
  return __builtin_amdgcn_exp2f(x);
}

// ---------------- cast x: fp32 -> bf16, [4096][1024] ----------------
__global__ __launch_bounds__(256) void cast_x_kernel(const float* __restrict__ x,
                                                     u16* __restrict__ xb) {
  int i = (blockIdx.x * 256 + threadIdx.x) * 8;
  const float4* p = reinterpret_cast<const float4*>(x + i);
  float4 a = p[0], b = p[1];
  u16x8 o;
  o[0] = f2bf(a.x); o[1] = f2bf(a.y); o[2] = f2bf(a.z); o[3] = f2bf(a.w);
  o[4] = f2bf(b.x); o[5] = f2bf(b.y); o[6] = f2bf(b.z); o[7] = f2bf(b.w);
  *reinterpret_cast<u16x8*>(xb + i) = o;
}

// -------- transpose + cast W [k][n] fp32 -> Wt [n][k] bf16 (z picks Wq/Wk/Wv/Wo) --------
__global__ __launch_bounds__(256) void transpose_w_kernel(
    const float* __restrict__ Wq, const float* __restrict__ Wk,
    const float* __restrict__ Wv, const float* __restrict__ Wo,
    u16* __restrict__ WT) {
  __shared__ float tile[64][65];
  int z = blockIdx.z;
  const float* W = (z == 0) ? Wq : (z == 1) ? Wk : (z == 2) ? Wv : Wo;
  float wscale = (z == 0) ? QSCALE : 1.0f;
  u16* out = WT + (size_t)z * 1024 * 1024;
  int k0 = blockIdx.y * 64, n0 = blockIdx.x * 64;
  int t = threadIdx.x;
  int rr = t >> 4;         // 0..15
  int cc = (t & 15) * 4;   // 0..60
#pragma unroll
  for (int j = 0; j < 4; ++j) {
    int r = rr + 16 * j;
    float4 v = *reinterpret_cast<const float4*>(W + (size_t)(k0 + r) * 1024 + n0 + cc);
    tile[r][cc + 0] = v.x; tile[r][cc + 1] = v.y;
    tile[r][cc + 2] = v.z; tile[r][cc + 3] = v.w;
  }
  __syncthreads();
#pragma unroll
  for (int j = 0; j < 4; ++j) {
    int nl = rr + 16 * j;
    u16x4 o;
#pragma unroll
    for (int i2 = 0; i2 < 4; ++i2) o[i2] = f2bf(tile[cc + i2][nl] * wscale);
    *reinterpret_cast<u16x4*>(out + (size_t)(n0 + nl) * 1024 + k0 + cc) = o;
  }
}

// ---------------- generic bf16 GEMM: C[4096][1024] = A @ Wt^T + bias ----------------
// MODE 0: bf16 out to [B,H,S,HD].  MODE 1: fp32 linear [m][n].  MODE 2: bf16 out TRANSPOSED
// to [B,H,HD,S] via LDS-transposed, s-coalesced stores.
template <int MODE>
static __device__ __forceinline__ void gemm_body(const u16* __restrict__ A,
                                                 const u16* __restrict__ Wt,
                                                 const float* __restrict__ bias,
                                                 float bscale,
                                                 void* __restrict__ Out) {
  __shared__ u16 As[128 * 32];
  __shared__ u16 Bs[128 * 32];
  int t = threadIdx.x;
  int lane = t & 63, wave = t >> 6;
  int g = lane >> 4, c = lane & 15;
  int m0 = blockIdx.y * 128, n0 = blockIdx.x * 128;
  int wm = (wave >> 1) * 64, wn = (wave & 1) * 64;

  f32x4 acc[4][4] = {};

  const u16* Ag = A + (size_t)(m0 + (t >> 2)) * 1024 + (t & 3) * 8;
  const u16* Bg = Wt + (size_t)(n0 + (t >> 2)) * 1024 + (t & 3) * 8;
  u16* Asd = As + t * 8;
  u16* Bsd = Bs + t * 8;

  for (int k0 = 0; k0 < 1024; k0 += 32) {
    gll16(Ag + k0, Asd);
    gll16(Ag + 64 * 1024 + k0, Asd + 64 * 32);
    gll16(Bg + k0, Bsd);
    gll16(Bg + 64 * 1024 + k0, Bsd + 64 * 32);
    __syncthreads();
    bf16x8 af[4], bfr[4];
#pragma unroll
    for (int i = 0; i < 4; ++i) {
      af[i]  = ldfrag(As + (wm + 16 * i + c) * 32 + g * 8);
      bfr[i] = ldfrag(Bs + (wn + 16 * i + c) * 32 + g * 8);
    }
#pragma unroll
    for (int i = 0; i < 4; ++i)
#pragma unroll
      for (int j = 0; j < 4; ++j)
        acc[i][j] = __builtin_amdgcn_mfma_f32_16x16x32_bf16(af[i], bfr[j], acc[i][j], 0, 0, 0);
    __syncthreads();
  }

  if (MODE == 0) {
    u16* out = (u16*)Out;
#pragma unroll
    for (int i = 0; i < 4; ++i) {
      int mb = m0 + wm + 16 * i + g * 4;
#pragma unroll
      for (int j = 0; j < 4; ++j) {
        int n = n0 + wn + 16 * j + c;
        float bv = bias[n] * bscale;
        int h = n >> 6, d = n & 63;
#pragma unroll
        for (int r = 0; r < 4; ++r) {
          int m = mb + r;
          int b = m >> 11, s = m & 2047;   // m = b*2048 + s
          out[((size_t)(b * 16 + h) * 2048 + s) * 64 + d] = f2bf(acc[i][j][r] + bv);
        }
      }
    }
  } else if (MODE == 2) {
    // V^T: per i-chunk, LDS-transpose the (2 panels)x(128 n)x(16 s) slab, then
    // stream each n-row's 16 contiguous s as two 16B stores (coalesced 32B bursts).
    u16* out = (u16*)Out;
    u16* tb = As;  // 2*128*16 u16 = 8 KB, exactly As
    int p = wave >> 1;
    // store-phase indices (per thread, i-invariant)
    int p2 = t >> 7, nl2 = t & 127;
    int n2 = n0 + nl2, h2 = n2 >> 6, d2 = n2 & 63;
    float bvj[4];
#pragma unroll
    for (int j = 0; j < 4; ++j) bvj[j] = bias[n0 + wn + 16 * j + c];
#pragma unroll
    for (int i = 0; i < 4; ++i) {
      __syncthreads();   // previous chunk's LDS reads done
#pragma unroll
      for (int j = 0; j < 4; ++j) {
        int nl = wn + 16 * j + c;
        u16x4 o4;
#pragma unroll
        for (int r = 0; r < 4; ++r) o4[r] = f2bf(acc[i][j][r] + bvj[j]);
        *reinterpret_cast<u16x4*>(&tb[(p * 128 + nl) * 16 + 4 * g]) = o4;
      }
      __syncthreads();
      int mb2 = m0 + p2 * 64 + 16 * i;
      int b2 = mb2 >> 11, s2 = mb2 & 2047;
      const u16x8* src = reinterpret_cast<const u16x8*>(&tb[t * 16]);
      u16* dst = out + ((size_t)(b2 * 16 + h2) * 64 + d2) * 2048 + s2;
      *reinterpret_cast<u16x8*>(dst) = src[0];
      *reinterpret_cast<u16x8*>(dst + 8) = src[1];
    }
  } else {
    float* out = (float*)Out;
#pragma unroll
    for (int i = 0; i < 4; ++i) {
      int mb = m0 + wm + 16 * i + g * 4;
#pragma unroll
      for (int j = 0; j < 4; ++j) {
        int n = n0 + wn + 16 * j + c;
        float bv = bias[n];
#pragma unroll
        for (int r = 0; r < 4; ++r)
          out[(size_t)(mb + r) * 1024 + n] = acc[i][j][r] + bv;
      }
    }
  }
}

__global__ __launch_bounds__(256) void qkv_gemm_kernel(
    const u16* __restrict__ xb, const u16* __restrict__ WT,
    const float* __restrict__ bq, const float* __restrict__ bk,
    const float* __restrict__ bv,
    u16* __restrict__ Q, u16* __restrict__ K, u16* __restrict__ V) {
  int z = blockIdx.z;
  const u16* Wt = WT + (size_t)z * 1024 * 1024;
  if (z == 0)      gemm_body<0>(xb, Wt, bq, QSCALE, Q);
  else if (z == 1) gemm_body<0>(xb, Wt, bk, 1.0f, K);
  else             gemm_body<2>(xb, Wt, bv, 1.0f, V);   // V stored transposed [B,H,HD,S]
}

__global__ __launch_bounds__(256) void oproj_kernel(
    const u16* __restrict__ attnb, const u16* __restrict__ WoT,
    const float* __restrict__ bo, float* __restrict__ out) {
  gemm_body<1>(attnb, WoT, bo, 1.0f, out);
}

// ---------------- flash attention (swapped-QK, frag-native LDS, KVBLK=64) ----------------
// Q,K: [B,H,S,HD] bf16 (Q pre-scaled). V: [B,H,HD,S] bf16 (transposed). Out: [B,S,D] bf16.
// Block: 4 waves x 16 q rows. KV tile = 64, double-buffered. LDS = 36 KB.
// lrow computed by MFMA row-sum (P . ones) directly in the o-layout (no shfl reduce).
__global__ __launch_bounds__(256) void attn_kernel(
    const u16* __restrict__ Q, const u16* __restrict__ K,
    const u16* __restrict__ V, u16* __restrict__ attn) {
  __shared__ u16 Kf[2][4096];
  __shared__ u16 Vt[2][4096];
  __shared__ u16 Pf[4][512];   // per-wave 1KB: 16q x 32kv bf16 (reused across m-halves)

  const int t = threadIdx.x;
  const int lane = t & 63, w = t >> 6;
  const int g = lane >> 4, c = lane & 15;

  // XCD-aware bijective swizzle (nwg=1024): each XCD's 128 blocks cover 4 (b,h) pairs
  // -> K/V working set 2 MB per XCD L2.
  int flat = blockIdx.x + 32 * (blockIdx.y + 16 * blockIdx.z);
  int sw = (flat & 7) * 128 + (flat >> 3);
  const int b = sw >> 9, h = (sw >> 5) & 15, q0 = (sw & 31) * 64;

  const u16* Qh = Q + ((size_t)(b * 16 + h) * 2048) * 64;
  const u16* Kh = K + ((size_t)(b * 16 + h) * 2048) * 64;
  const u16* VTh = V + ((size_t)(b * 16 + h) * 64) * 2048;

  const int qw = q0 + w * 16;
  // Q B-frags, held in registers for the whole kernel
  bf16x8 qf0 = ldfrag(Qh + (size_t)(qw + c) * 64 + 8 * g);
  bf16x8 qf1 = ldfrag(Qh + (size_t)(qw + c) * 64 + 32 + 8 * g);

  // all-ones B-frag for the MFMA row-sum
  bf16x8 ones;
  {
    u16x8 tmp;
#pragma unroll
    for (int l = 0; l < 8; ++l) tmp[l] = 0x3F80;
    ones = __builtin_bit_cast(bf16x8, tmp);
  }

  // per-lane V^T staging source (wave w stages d rows [16w, 16w+16))
  const u16* vsrc = VTh + (size_t)(16 * w + (lane >> 3)) * 2048 +
                    (((lane & 7) ^ ((lane >> 3) & 7)) * 8);
  u16* vdst0 = &Vt[0][16 * w * 64];
  u16* vdst1 = &Vt[1][16 * w * 64];

  // hoisted loop-invariant LDS offsets (u16 units)
  const int koff = g * 128 + c * 8;                 // K-frag base; +t4*1024+u*512
  int vb_off[2];
#pragma unroll
  for (int m = 0; m < 2; ++m)
    vb_off[m] = c * 64 + (((4 * m + g) ^ (c & 7)) * 8);  // V-frag base; +j*1024
  const int pa_off = (g * 16 + c) * 8;

  f32x4 o[4] = {};
  f32x4 lsum = {};
  float mrow = -3e38f;

  // ---- prologue: stage tile 0 ----
  {
#pragma unroll
    for (int i = 0; i < 2; ++i) {
      int unit = ((w * 2 + i) << 6) | lane;
      int cc = unit & 15, gg = (unit >> 4) & 3, uu = (unit >> 6) & 1, t4 = (unit >> 7) & 3;
      gll16(Kh + (size_t)(16 * t4 + cc) * 64 + 32 * uu + 8 * gg, &Kf[0][unit * 8]);
      gll16(vsrc + (size_t)(8 * i) * 2048, vdst0 + i * 512);
    }
    __syncthreads();
  }

  int cur = 0;
  for (int kv0 = 0; kv0 < 2048; kv0 += 64) {
    const int nxt = kv0 + 64;
    const bool pfch = nxt < 2048;
    if (pfch) {
      u16* vdst = cur ? vdst0 : vdst1;
#pragma unroll
      for (int i = 0; i < 2; ++i) {
        int unit = ((w * 2 + i) << 6) | lane;
        int cc = unit & 15, gg = (unit >> 4) & 3, uu = (unit >> 6) & 1, t4 = (unit >> 7) & 3;
        gll16(Kh + (size_t)(nxt + 16 * t4 + cc) * 64 + 32 * uu + 8 * gg,
              &Kf[cur ^ 1][unit * 8]);
        gll16(vsrc + (size_t)(8 * i) * 2048 + nxt, vdst + i * 512);
      }
    }

    // ---- swapped QK^T: st[t4] = K(16 kv) . Q^T -> S^T[kv][q], q = c per lane ----
    const u16* kb = &Kf[cur][koff];
    f32x4 st[4];
    __builtin_amdgcn_s_setprio(1);
#pragma unroll
    for (int t4 = 0; t4 < 4; ++t4) {
      f32x4 acc = {};
      acc = __builtin_amdgcn_mfma_f32_16x16x32_bf16(
          ldfrag(kb + t4 * 1024), qf0, acc, 0, 0, 0);
      st[t4] = __builtin_amdgcn_mfma_f32_16x16x32_bf16(
          ldfrag(kb + t4 * 1024 + 512), qf1, acc, 0, 0, 0);
    }
    __builtin_amdgcn_s_setprio(0);

    // ---- online softmax over 64-kv tile (scores already in log2 units) ----
    float tmq[4];
#pragma unroll
    for (int t4 = 0; t4 < 4; ++t4)
      tmq[t4] = fmaxf(fmaxf(st[t4][0], st[t4][1]), fmaxf(st[t4][2], st[t4][3]));
    float tm = fmaxf(fmaxf(tmq[0], tmq[1]), fmaxf(tmq[2], tmq[3]));
    tm = fmaxf(tm, __shfl_xor(tm, 16));
    tm = fmaxf(tm, __shfl_xor(tm, 32));
    // T13 defer-max: only rescale when the max grew by >8 (log2 units; P <= 2^8)
    const bool grow = __any(tm > mrow + 8.0f);
    if (grow) {
      float nm = fmaxf(mrow, tm);
      float f = fexp2(mrow - nm);
      mrow = nm;
#pragma unroll
      for (int r = 0; r < 4; ++r) {
        float fr = __shfl(f, 4 * g + r);   // f lives at lanes indexed by q=c
        lsum[r] *= fr;
#pragma unroll
        for (int j = 0; j < 4; ++j) o[j][r] *= fr;
      }
    }
#pragma unroll
    for (int t4 = 0; t4 < 4; ++t4)
#pragma unroll
      for (int r = 0; r < 4; ++r) st[t4][r] = fexp2(st[t4][r] - mrow);

    // ---- pack P (per 32-kv half) into per-wave A-frag layout, then PV on that half ----
    u32* pd = (u32*)&Pf[w][0];
#pragma unroll
    for (int m = 0; m < 2; ++m) {
#pragma unroll
      for (int tt = 0; tt < 2; ++tt) {
        int t4 = 2 * m + tt;
        u32 w0 = cvt_pk_bf16(st[t4][0], st[t4][1]);
        u32 w1 = cvt_pk_bf16(st[t4][2], st[t4][3]);
        int gp = (2 * t4 + (g >> 1)) & 3;
        int base = (gp * 16 + c) * 4 + 2 * (g & 1);
        *reinterpret_cast<u64*>(&pd[base]) = (u64)w0 | ((u64)w1 << 32);
      }
      bf16x8 pa = ldfrag(&Pf[w][pa_off]);
      __builtin_amdgcn_s_setprio(1);
#pragma unroll
      for (int j = 0; j < 4; ++j) {
        bf16x8 vb = ldfrag(&Vt[cur][vb_off[m] + j * 1024]);
        o[j] = __builtin_amdgcn_mfma_f32_16x16x32_bf16(pa, vb, o[j], 0, 0, 0);
      }
      lsum = __builtin_amdgcn_mfma_f32_16x16x32_bf16(pa, ones, lsum, 0, 0, 0);
      __builtin_amdgcn_s_setprio(0);
    }

    __syncthreads();
    cur ^= 1;
  }

  // ---- epilogue: normalize, write attn[B,S,D] (O lane layout: q=4g+r, d=16j+c) ----
  float rinv[4];
#pragma unroll
  for (int r = 0; r < 4; ++r) rinv[r] = 1.f / lsum[r];
#pragma unroll
  for (int j = 0; j < 4; ++j)
#pragma unroll
    for (int r = 0; r < 4; ++r) {
      int s = qw + 4 * g + r;
      attn[(size_t)(b * 2048 + s) * 1024 + h * 64 + 16 * j + c] = f2bf(o[j][r] * rinv[r]);
    }
}

extern "C" void kernel_launch(void* const* d_in, const int* in_sizes, int n_in,
                              void* d_out, int out_size, void* d_ws, size_t ws_size,
                              hipStream_t stream) {
  const float* x  = (const float*)d_in[0];
  const float* Wq = (const float*)d_in[1];
  const float* bq = (const float*)d_in[2];
  const float* Wk = (const float*)d_in[3];
  const float* bk = (const float*)d_in[4];
  const float* Wv = (const float*)d_in[5];
  const float* bv = (const float*)d_in[6];
  const float* Wo = (const float*)d_in[7];
  const float* bo = (const float*)d_in[8];
  float* out = (float*)d_out;
  u16* ws = (u16*)d_ws;

  // workspace layout (u16 elems): xb 4M | WT 4x1M | Q 4M | K 4M | V^T 4M  => 40 MB
  u16* xb    = ws;
  u16* WT    = ws + (size_t)4 * 1024 * 1024;
  u16* Qb    = ws + (size_t)8 * 1024 * 1024;
  u16* Kb    = ws + (size_t)12 * 1024 * 1024;
  u16* Vb    = ws + (size_t)16 * 1024 * 1024;
  u16* attnb = xb;  // xb dead after QKV GEMM; reuse for attn output

  cast_x_kernel<<<2048, 256, 0, stream>>>(x, xb);
  transpose_w_kernel<<<dim3(16, 16, 4), 256, 0, stream>>>(Wq, Wk, Wv, Wo, WT);
  qkv_gemm_kernel<<<dim3(8, 32, 3), 256, 0, stream>>>(xb, WT, bq, bk, bv, Qb, Kb, Vb);
  attn_kernel<<<dim3(32, 16, 2), 256, 0, stream>>>(Qb, Kb, Vb, attnb);
  oproj_kernel<<<dim3(8, 32), 256, 0, stream>>>(attnb, WT + (size_t)3 * 1024 * 1024, bo, out);
}

// Round 8
// 151.955 us; speedup vs baseline: 1.0753x; 1.0334x over previous
//
#include <hip/hip_runtime.h>
#include <stdint.h>

// B=2, S=2048, D=1024, H=16, HD=64
typedef unsigned short u16;
typedef unsigned int u32;
typedef unsigned long long u64;
typedef __bf16 bf16x8 __attribute__((ext_vector_type(8)));
typedef float f32x4 __attribute__((ext_vector_type(4)));
typedef unsigned short u16x8 __attribute__((ext_vector_type(8)));
typedef unsigned short u16x4 __attribute__((ext_vector_type(4)));

#define QSCALE 0.1803368801111204f  // 0.125 * log2(e): folded into Wq/bq so softmax uses exp2

static __device__ __forceinline__ u16 f2bf(float f) {
  unsigned u = __builtin_bit_cast(unsigned, f);
  u += 0x7fffu + ((u >> 16) & 1u);   // RNE
  return (u16)(u >> 16);
}

static __device__ __forceinline__ bf16x8 ldfrag(const u16* p) {
  return *reinterpret_cast<const bf16x8*>(p);
}

static __device__ __forceinline__ void gll16(const u16* g, u16* l) {
  __builtin_amdgcn_global_load_lds(
      (const __attribute__((address_space(1))) void*)g,
      (__attribute__((address_space(3))) void*)l, 16, 0, 0);
}

static __device__ __forceinline__ u32 cvt_pk_bf16(float lo, float hi) {
  u32 r;
  asm("v_cvt_pk_bf16_f32 %0, %1, %2" : "=v"(r) : "v"(lo), "v"(hi));
  return r;
}

// raw v_exp_f32 (2^x): avoids the non-fast-math denormal-guard expansion of exp2f.
static __device__ __forceinline__ float fexp2(float x) {
  return __builtin_amdgcn_exp2f(x);
}

// ---------------- cast x: fp32 -> bf16, [4096][1024] ----------------
__global__ __launch_bounds__(256) void cast_x_kernel(const float* __restrict__ x,
                                                     u16* __restrict__ xb) {
  int i = (blockIdx.x * 256 + threadIdx.x) * 8;
  const float4* p = reinterpret_cast<const float4*>(x + i);
  float4 a = p[0], b = p[1];
  u16x8 o;
  o[0] = f2bf(a.x); o[1] = f2bf(a.y); o[2] = f2bf(a.z); o[3] = f2bf(a.w);
  o[4] = f2bf(b.x); o[5] = f2bf(b.y); o[6] = f2bf(b.z); o[7] = f2bf(b.w);
  *reinterpret_cast<u16x8*>(xb + i) = o;
}

// -------- transpose + cast W [k][n] fp32 -> Wt [n][k] bf16 (z picks Wq/Wk/Wv/Wo) --------
__global__ __launch_bounds__(256) void transpose_w_kernel(
    const float* __restrict__ Wq, const float* __restrict__ Wk,
    const float* __restrict__ Wv, const float* __restrict__ Wo,
    u16* __restrict__ WT) {
  __shared__ float tile[64][65];
  int z = blockIdx.z;
  const float* W = (z == 0) ? Wq : (z == 1) ? Wk : (z == 2) ? Wv : Wo;
  float wscale = (z == 0) ? QSCALE : 1.0f;
  u16* out = WT + (size_t)z * 1024 * 1024;
  int k0 = blockIdx.y * 64, n0 = blockIdx.x * 64;
  int t = threadIdx.x;
  int rr = t >> 4;         // 0..15
  int cc = (t & 15) * 4;   // 0..60
#pragma unroll
  for (int j = 0; j < 4; ++j) {
    int r = rr + 16 * j;
    float4 v = *reinterpret_cast<const float4*>(W + (size_t)(k0 + r) * 1024 + n0 + cc);
    tile[r][cc + 0] = v.x; tile[r][cc + 1] = v.y;
    tile[r][cc + 2] = v.z; tile[r][cc + 3] = v.w;
  }
  __syncthreads();
#pragma unroll
  for (int j = 0; j < 4; ++j) {
    int nl = rr + 16 * j;
    u16x4 o;
#pragma unroll
    for (int i2 = 0; i2 < 4; ++i2) o[i2] = f2bf(tile[cc + i2][nl] * wscale);
    *reinterpret_cast<u16x4*>(out + (size_t)(n0 + nl) * 1024 + k0 + cc) = o;
  }
}

// ---------------- QKV bf16 GEMM: C[4096][1024] = A @ Wt^T + bias ----------------
// MODE 0 (Q/K): SWAPPED mfma (acc r -> n/d contiguous) -> direct u16x4 stores to [B,H,S,HD].
// MODE 2 (V):   unswapped (acc r -> s contiguous) -> LDS re-tile -> fully-coalesced
//               256B-per-row stores to V^T [B,H,HD,S].
template <int MODE>
static __device__ __forceinline__ void gemm_body(const u16* __restrict__ A,
                                                 const u16* __restrict__ Wt,
                                                 const float* __restrict__ bias,
                                                 float bscale,
                                                 void* __restrict__ Out) {
  __shared__ u16 smem[17408];            // As(4096) | Bs(4096); epilogue tb overlays (MODE 2)
  u16* As = smem;
  u16* Bs = smem + 4096;
  int t = threadIdx.x;
  int lane = t & 63, wave = t >> 6;
  int g = lane >> 4, c = lane & 15;
  int m0 = blockIdx.y * 128, n0 = blockIdx.x * 128;
  int wm = (wave >> 1) * 64, wn = (wave & 1) * 64;

  f32x4 acc[4][4] = {};

  const u16* Ag = A + (size_t)(m0 + (t >> 2)) * 1024 + (t & 3) * 8;
  const u16* Bg = Wt + (size_t)(n0 + (t >> 2)) * 1024 + (t & 3) * 8;
  u16* Asd = As + t * 8;
  u16* Bsd = Bs + t * 8;

  for (int k0 = 0; k0 < 1024; k0 += 32) {
    gll16(Ag + k0, Asd);
    gll16(Ag + 64 * 1024 + k0, Asd + 64 * 32);
    gll16(Bg + k0, Bsd);
    gll16(Bg + 64 * 1024 + k0, Bsd + 64 * 32);
    __syncthreads();
    bf16x8 af[4], bfr[4];
#pragma unroll
    for (int i = 0; i < 4; ++i) {
      af[i]  = ldfrag(As + (wm + 16 * i + c) * 32 + g * 8);
      bfr[i] = ldfrag(Bs + (wn + 16 * i + c) * 32 + g * 8);
    }
#pragma unroll
    for (int i = 0; i < 4; ++i)
#pragma unroll
      for (int j = 0; j < 4; ++j) {
        if (MODE == 2)
          acc[i][j] = __builtin_amdgcn_mfma_f32_16x16x32_bf16(af[i], bfr[j], acc[i][j], 0, 0, 0);
        else
          acc[i][j] = __builtin_amdgcn_mfma_f32_16x16x32_bf16(bfr[j], af[i], acc[i][j], 0, 0, 0);
      }
    __syncthreads();
  }

  if (MODE == 0) {
    // swapped: acc[i][j][r] = C[m = wm+16i+c][n = wn+16j+4g+r]
    u16* out = (u16*)Out;
    int nj[4], hj[4], dj[4];
    f32x4 bbj[4];
#pragma unroll
    for (int j = 0; j < 4; ++j) {
      nj[j] = n0 + wn + 16 * j + 4 * g;
      hj[j] = nj[j] >> 6; dj[j] = nj[j] & 63;
      f32x4 bb = *reinterpret_cast<const f32x4*>(&bias[nj[j]]);
#pragma unroll
      for (int r = 0; r < 4; ++r) bbj[j][r] = bb[r] * bscale;
    }
#pragma unroll
    for (int i = 0; i < 4; ++i) {
      int m = m0 + wm + 16 * i + c;
      int b2 = m >> 11, s2 = m & 2047;
#pragma unroll
      for (int j = 0; j < 4; ++j) {
        u16x4 o4;
#pragma unroll
        for (int r = 0; r < 4; ++r) o4[r] = f2bf(acc[i][j][r] + bbj[j][r]);
        *reinterpret_cast<u16x4*>(
            out + ((size_t)(b2 * 16 + hj[j]) * 2048 + s2) * 64 + dj[j]) = o4;
      }
    }
  } else {
    // V^T: unswapped acc (r -> s). Re-tile via tb[n_local 128][s_local 128 pad 136].
    u16* out = (u16*)Out;
    u16* tb = smem;
    float bvj[4];
#pragma unroll
    for (int j = 0; j < 4; ++j) bvj[j] = bias[n0 + wn + 16 * j + c];
#pragma unroll
    for (int i = 0; i < 4; ++i)
#pragma unroll
      for (int j = 0; j < 4; ++j) {
        u16x4 o4;
#pragma unroll
        for (int r = 0; r < 4; ++r) o4[r] = f2bf(acc[i][j][r] + bvj[j]);
        *reinterpret_cast<u16x4*>(&tb[(wn + 16 * j + c) * 136 + wm + 16 * i + 4 * g]) = o4;
      }
    __syncthreads();
    int b2 = m0 >> 11, s0 = m0 & 2047;
    int slot = lane & 15;
#pragma unroll
    for (int k = 0; k < 8; ++k) {
      int row = wave * 32 + k * 4 + (lane >> 4);   // n_local 0..127
      u16x8 v = *reinterpret_cast<const u16x8*>(&tb[row * 136 + slot * 8]);
      int n = n0 + row, h2 = n >> 6, d2 = n & 63;
      *reinterpret_cast<u16x8*>(
          out + ((size_t)(b2 * 16 + h2) * 64 + d2) * 2048 + s0 + slot * 8) = v;
    }
  }
}

__global__ __launch_bounds__(256) void qkv_gemm_kernel(
    const u16* __restrict__ xb, const u16* __restrict__ WT,
    const float* __restrict__ bq, const float* __restrict__ bk,
    const float* __restrict__ bv,
    u16* __restrict__ Q, u16* __restrict__ K, u16* __restrict__ V) {
  int z = blockIdx.z;
  const u16* Wt = WT + (size_t)z * 1024 * 1024;
  if (z == 0)      gemm_body<0>(xb, Wt, bq, QSCALE, Q);
  else if (z == 1) gemm_body<0>(xb, Wt, bk, 1.0f, K);
  else             gemm_body<2>(xb, Wt, bv, 1.0f, V);   // V stored transposed [B,H,HD,S]
}

// ---------------- out-projection: 512 threads (8 waves, 32x64 each), fp32 out ----------------
__global__ __launch_bounds__(512) void oproj_kernel(
    const u16* __restrict__ A, const u16* __restrict__ Wt,
    const float* __restrict__ bias, float* __restrict__ out) {
  __shared__ u16 As[128 * 32];
  __shared__ u16 Bs[128 * 32];
  int t = threadIdx.x;
  int lane = t & 63, wave = t >> 6;          // 8 waves
  int g = lane >> 4, c = lane & 15;
  int m0 = blockIdx.y * 128, n0 = blockIdx.x * 128;
  int wm = (wave >> 1) * 32, wn = (wave & 1) * 64;

  f32x4 acc[2][4] = {};

  const u16* Ag = A + (size_t)(m0 + (t >> 2)) * 1024 + (t & 3) * 8;
  const u16* Bg = Wt + (size_t)(n0 + (t >> 2)) * 1024 + (t & 3) * 8;
  u16* Asd = As + t * 8;     // 512 threads x 16B cover the full 8 KB tile
  u16* Bsd = Bs + t * 8;

  for (int k0 = 0; k0 < 1024; k0 += 32) {
    gll16(Ag + k0, Asd);
    gll16(Bg + k0, Bsd);
    __syncthreads();
    bf16x8 af[2], bfr[4];
#pragma unroll
    for (int i = 0; i < 2; ++i) af[i] = ldfrag(As + (wm + 16 * i + c) * 32 + g * 8);
#pragma unroll
    for (int j = 0; j < 4; ++j) bfr[j] = ldfrag(Bs + (wn + 16 * j + c) * 32 + g * 8);
#pragma unroll
    for (int i = 0; i < 2; ++i)
#pragma unroll
      for (int j = 0; j < 4; ++j)   // swapped: acc r -> n contiguous
        acc[i][j] = __builtin_amdgcn_mfma_f32_16x16x32_bf16(bfr[j], af[i], acc[i][j], 0, 0, 0);
    __syncthreads();
  }

  f32x4 bbj[4];
#pragma unroll
  for (int j = 0; j < 4; ++j)
    bbj[j] = *reinterpret_cast<const f32x4*>(&bias[n0 + wn + 16 * j + 4 * g]);
#pragma unroll
  for (int i = 0; i < 2; ++i) {
    int m = m0 + wm + 16 * i + c;
#pragma unroll
    for (int j = 0; j < 4; ++j) {
      f32x4 v = acc[i][j] + bbj[j];
      *reinterpret_cast<f32x4*>(out + (size_t)m * 1024 + n0 + wn + 16 * j + 4 * g) = v;
    }
  }
}

// ---------------- flash attention (swapped-QK, frag-native LDS, KVBLK=64) ----------------
__global__ __launch_bounds__(256) void attn_kernel(
    const u16* __restrict__ Q, const u16* __restrict__ K,
    const u16* __restrict__ V, u16* __restrict__ attn) {
  __shared__ u16 Kf[2][4096];
  __shared__ u16 Vt[2][4096];
  __shared__ u16 Pf[4][512];   // per-wave 1KB: 16q x 32kv bf16 (reused across m-halves)

  const int t = threadIdx.x;
  const int lane = t & 63, w = t >> 6;
  const int g = lane >> 4, c = lane & 15;

  // XCD-aware bijective swizzle (nwg=1024): each XCD's 128 blocks cover 4 (b,h) pairs
  int flat = blockIdx.x + 32 * (blockIdx.y + 16 * blockIdx.z);
  int sw = (flat & 7) * 128 + (flat >> 3);
  const int b = sw >> 9, h = (sw >> 5) & 15, q0 = (sw & 31) * 64;

  const u16* Qh = Q + ((size_t)(b * 16 + h) * 2048) * 64;
  const u16* Kh = K + ((size_t)(b * 16 + h) * 2048) * 64;
  const u16* VTh = V + ((size_t)(b * 16 + h) * 64) * 2048;

  const int qw = q0 + w * 16;
  bf16x8 qf0 = ldfrag(Qh + (size_t)(qw + c) * 64 + 8 * g);
  bf16x8 qf1 = ldfrag(Qh + (size_t)(qw + c) * 64 + 32 + 8 * g);

  bf16x8 ones;
  {
    u16x8 tmp;
#pragma unroll
    for (int l = 0; l < 8; ++l) tmp[l] = 0x3F80;
    ones = __builtin_bit_cast(bf16x8, tmp);
  }

  const u16* vsrc = VTh + (size_t)(16 * w + (lane >> 3)) * 2048 +
                    (((lane & 7) ^ ((lane >> 3) & 7)) * 8);
  u16* vdst0 = &Vt[0][16 * w * 64];
  u16* vdst1 = &Vt[1][16 * w * 64];

  const int koff = g * 128 + c * 8;
  int vb_off[2];
#pragma unroll
  for (int m = 0; m < 2; ++m)
    vb_off[m] = c * 64 + (((4 * m + g) ^ (c & 7)) * 8);
  const int pa_off = (g * 16 + c) * 8;

  f32x4 o[4] = {};
  f32x4 lsum = {};
  float mrow = -3e38f;

  {
#pragma unroll
    for (int i = 0; i < 2; ++i) {
      int unit = ((w * 2 + i) << 6) | lane;
      int cc = unit & 15, gg = (unit >> 4) & 3, uu = (unit >> 6) & 1, t4 = (unit >> 7) & 3;
      gll16(Kh + (size_t)(16 * t4 + cc) * 64 + 32 * uu + 8 * gg, &Kf[0][unit * 8]);
      gll16(vsrc + (size_t)(8 * i) * 2048, vdst0 + i * 512);
    }
    __syncthreads();
  }

  int cur = 0;
  for (int kv0 = 0; kv0 < 2048; kv0 += 64) {
    const int nxt = kv0 + 64;
    const bool pfch = nxt < 2048;
    if (pfch) {
      u16* vdst = cur ? vdst0 : vdst1;
#pragma unroll
      for (int i = 0; i < 2; ++i) {
        int unit = ((w * 2 + i) << 6) | lane;
        int cc = unit & 15, gg = (unit >> 4) & 3, uu = (unit >> 6) & 1, t4 = (unit >> 7) & 3;
        gll16(Kh + (size_t)(nxt + 16 * t4 + cc) * 64 + 32 * uu + 8 * gg,
              &Kf[cur ^ 1][unit * 8]);
        gll16(vsrc + (size_t)(8 * i) * 2048 + nxt, vdst + i * 512);
      }
    }

    const u16* kb = &Kf[cur][koff];
    f32x4 st[4];
    __builtin_amdgcn_s_setprio(1);
#pragma unroll
    for (int t4 = 0; t4 < 4; ++t4) {
      f32x4 acc = {};
      acc = __builtin_amdgcn_mfma_f32_16x16x32_bf16(
          ldfrag(kb + t4 * 1024), qf0, acc, 0, 0, 0);
      st[t4] = __builtin_amdgcn_mfma_f32_16x16x32_bf16(
          ldfrag(kb + t4 * 1024 + 512), qf1, acc, 0, 0, 0);
    }
    __builtin_amdgcn_s_setprio(0);

    float tmq[4];
#pragma unroll
    for (int t4 = 0; t4 < 4; ++t4)
      tmq[t4] = fmaxf(fmaxf(st[t4][0], st[t4][1]), fmaxf(st[t4][2], st[t4][3]));
    float tm = fmaxf(fmaxf(tmq[0], tmq[1]), fmaxf(tmq[2], tmq[3]));
    tm = fmaxf(tm, __shfl_xor(tm, 16));
    tm = fmaxf(tm, __shfl_xor(tm, 32));
    const bool grow = __any(tm > mrow + 8.0f);
    if (grow) {
      float nm = fmaxf(mrow, tm);
      float f = fexp2(mrow - nm);
      mrow = nm;
#pragma unroll
      for (int r = 0; r < 4; ++r) {
        float fr = __shfl(f, 4 * g + r);
        lsum[r] *= fr;
#pragma unroll
        for (int j = 0; j < 4; ++j) o[j][r] *= fr;
      }
    }
#pragma unroll
    for (int t4 = 0; t4 < 4; ++t4)
#pragma unroll
      for (int r = 0; r < 4; ++r) st[t4][r] = fexp2(st[t4][r] - mrow);

    u32* pd = (u32*)&Pf[w][0];
#pragma unroll
    for (int m = 0; m < 2; ++m) {
#pragma unroll
      for (int tt = 0; tt < 2; ++tt) {
        int t4 = 2 * m + tt;
        u32 w0 = cvt_pk_bf16(st[t4][0], st[t4][1]);
        u32 w1 = cvt_pk_bf16(st[t4][2], st[t4][3]);
        int gp = (2 * t4 + (g >> 1)) & 3;
        int base = (gp * 16 + c) * 4 + 2 * (g & 1);
        *reinterpret_cast<u64*>(&pd[base]) = (u64)w0 | ((u64)w1 << 32);
      }
      bf16x8 pa = ldfrag(&Pf[w][pa_off]);
      __builtin_amdgcn_s_setprio(1);
#pragma unroll
      for (int j = 0; j < 4; ++j) {
        bf16x8 vb = ldfrag(&Vt[cur][vb_off[m] + j * 1024]);
        o[j] = __builtin_amdgcn_mfma_f32_16x16x32_bf16(pa, vb, o[j], 0, 0, 0);
      }
      lsum = __builtin_amdgcn_mfma_f32_16x16x32_bf16(pa, ones, lsum, 0, 0, 0);
      __builtin_amdgcn_s_setprio(0);
    }

    __syncthreads();
    cur ^= 1;
  }

  float rinv[4];
#pragma unroll
  for (int r = 0; r < 4; ++r) rinv[r] = 1.f / lsum[r];
#pragma unroll
  for (int j = 0; j < 4; ++j)
#pragma unroll
    for (int r = 0; r < 4; ++r) {
      int s = qw + 4 * g + r;
      attn[(size_t)(b * 2048 + s) * 1024 + h * 64 + 16 * j + c] = f2bf(o[j][r] * rinv[r]);
    }
}

extern "C" void kernel_launch(void* const* d_in, const int* in_sizes, int n_in,
                              void* d_out, int out_size, void* d_ws, size_t ws_size,
                              hipStream_t stream) {
  const float* x  = (const float*)d_in[0];
  const float* Wq = (const float*)d_in[1];
  const float* bq = (const float*)d_in[2];
  const float* Wk = (const float*)d_in[3];
  const float* bk = (const float*)d_in[4];
  const float* Wv = (const float*)d_in[5];
  const float* bv = (const float*)d_in[6];
  const float* Wo = (const float*)d_in[7];
  const float* bo = (const float*)d_in[8];
  float* out = (float*)d_out;
  u16* ws = (u16*)d_ws;

  // workspace layout (u16 elems): xb 4M | WT 4x1M | Q 4M | K 4M | V^T 4M  => 40 MB
  u16* xb    = ws;
  u16* WT    = ws + (size_t)4 * 1024 * 1024;
  u16* Qb    = ws + (size_t)8 * 1024 * 1024;
  u16* Kb    = ws + (size_t)12 * 1024 * 1024;
  u16* Vb    = ws + (size_t)16 * 1024 * 1024;
  u16* attnb = xb;  // xb dead after QKV GEMM; reuse for attn output

  cast_x_kernel<<<2048, 256, 0, stream>>>(x, xb);
  transpose_w_kernel<<<dim3(16, 16, 4), 256, 0, stream>>>(Wq, Wk, Wv, Wo, WT);
  qkv_gemm_kernel<<<dim3(8, 32, 3), 256, 0, stream>>>(xb, WT, bq, bk, bv, Qb, Kb, Vb);
  attn_kernel<<<dim3(32, 16, 2), 256, 0, stream>>>(Qb, Kb, Vb, attnb);
  oproj_kernel<<<dim3(8, 32), 512, 0, stream>>>(attnb, WT + (size_t)3 * 1024 * 1024, bo, out);
}

// Round 9
// 139.389 us; speedup vs baseline: 1.1722x; 1.0902x over previous
//
#include <hip/hip_runtime.h>
#include <stdint.h>

// B=2, S=2048, D=1024, H=16, HD=64
typedef unsigned short u16;
typedef unsigned int u32;
typedef unsigned long long u64;
typedef __bf16 bf16x8 __attribute__((ext_vector_type(8)));
typedef float f32x4 __attribute__((ext_vector_type(4)));
typedef unsigned short u16x8 __attribute__((ext_vector_type(8)));
typedef unsigned short u16x4 __attribute__((ext_vector_type(4)));

#define QSCALE 0.1803368801111204f  // 0.125 * log2(e): folded into Wq/bq so softmax uses exp2

static __device__ __forceinline__ u16 f2bf(float f) {
  unsigned u = __builtin_bit_cast(unsigned, f);
  u += 0x7fffu + ((u >> 16) & 1u);   // RNE
  return (u16)(u >> 16);
}

static __device__ __forceinline__ bf16x8 ldfrag(const u16* p) {
  return *reinterpret_cast<const bf16x8*>(p);
}

static __device__ __forceinline__ void gll16(const u16* g, u16* l) {
  __builtin_amdgcn_global_load_lds(
      (const __attribute__((address_space(1))) void*)g,
      (__attribute__((address_space(3))) void*)l, 16, 0, 0);
}

static __device__ __forceinline__ u32 cvt_pk_bf16(float lo, float hi) {
  u32 r;
  asm("v_cvt_pk_bf16_f32 %0, %1, %2" : "=v"(r) : "v"(lo), "v"(hi));
  return r;
}

// raw v_exp_f32 (2^x): avoids the non-fast-math denormal-guard expansion of exp2f.
static __device__ __forceinline__ float fexp2(float x) {
  return __builtin_amdgcn_exp2f(x);
}

// 3-ary max (clang fuses to v_max3_f32)
static __device__ __forceinline__ float fm3(float a, float b, float c) {
  return fmaxf(fmaxf(a, b), c);
}

// ---------------- cast x: fp32 -> bf16, [4096][1024] ----------------
__global__ __launch_bounds__(256) void cast_x_kernel(const float* __restrict__ x,
                                                     u16* __restrict__ xb) {
  int i = (blockIdx.x * 256 + threadIdx.x) * 8;
  const float4* p = reinterpret_cast<const float4*>(x + i);
  float4 a = p[0], b = p[1];
  u16x8 o;
  o[0] = f2bf(a.x); o[1] = f2bf(a.y); o[2] = f2bf(a.z); o[3] = f2bf(a.w);
  o[4] = f2bf(b.x); o[5] = f2bf(b.y); o[6] = f2bf(b.z); o[7] = f2bf(b.w);
  *reinterpret_cast<u16x8*>(xb + i) = o;
}

// -------- transpose + cast W [k][n] fp32 -> Wt [n][k] bf16 (z picks Wq/Wk/Wv/Wo) --------
__global__ __launch_bounds__(256) void transpose_w_kernel(
    const float* __restrict__ Wq, const float* __restrict__ Wk,
    const float* __restrict__ Wv, const float* __restrict__ Wo,
    u16* __restrict__ WT) {
  __shared__ float tile[64][65];
  int z = blockIdx.z;
  const float* W = (z == 0) ? Wq : (z == 1) ? Wk : (z == 2) ? Wv : Wo;
  float wscale = (z == 0) ? QSCALE : 1.0f;
  u16* out = WT + (size_t)z * 1024 * 1024;
  int k0 = blockIdx.y * 64, n0 = blockIdx.x * 64;
  int t = threadIdx.x;
  int rr = t >> 4;         // 0..15
  int cc = (t & 15) * 4;   // 0..60
#pragma unroll
  for (int j = 0; j < 4; ++j) {
    int r = rr + 16 * j;
    float4 v = *reinterpret_cast<const float4*>(W + (size_t)(k0 + r) * 1024 + n0 + cc);
    tile[r][cc + 0] = v.x; tile[r][cc + 1] = v.y;
    tile[r][cc + 2] = v.z; tile[r][cc + 3] = v.w;
  }
  __syncthreads();
#pragma unroll
  for (int j = 0; j < 4; ++j) {
    int nl = rr + 16 * j;
    u16x4 o;
#pragma unroll
    for (int i2 = 0; i2 < 4; ++i2) o[i2] = f2bf(tile[cc + i2][nl] * wscale);
    *reinterpret_cast<u16x4*>(out + (size_t)(n0 + nl) * 1024 + k0 + cc) = o;
  }
}

// ---------------- QKV bf16 GEMM: C[4096][1024] = A @ Wt^T + bias ----------------
// MODE 0 (Q/K): SWAPPED mfma (acc r -> n/d contiguous) -> direct u16x4 stores to [B,H,S,HD].
// MODE 2 (V):   unswapped (acc r -> s contiguous) -> LDS re-tile -> fully-coalesced
//               256B-per-row stores to V^T [B,H,HD,S].
template <int MODE>
static __device__ __forceinline__ void gemm_body(const u16* __restrict__ A,
                                                 const u16* __restrict__ Wt,
                                                 const float* __restrict__ bias,
                                                 float bscale,
                                                 void* __restrict__ Out) {
  __shared__ u16 smem[17408];            // As(4096) | Bs(4096); epilogue tb overlays (MODE 2)
  u16* As = smem;
  u16* Bs = smem + 4096;
  int t = threadIdx.x;
  int lane = t & 63, wave = t >> 6;
  int g = lane >> 4, c = lane & 15;
  int m0 = blockIdx.y * 128, n0 = blockIdx.x * 128;
  int wm = (wave >> 1) * 64, wn = (wave & 1) * 64;

  f32x4 acc[4][4] = {};

  const u16* Ag = A + (size_t)(m0 + (t >> 2)) * 1024 + (t & 3) * 8;
  const u16* Bg = Wt + (size_t)(n0 + (t >> 2)) * 1024 + (t & 3) * 8;
  u16* Asd = As + t * 8;
  u16* Bsd = Bs + t * 8;

  for (int k0 = 0; k0 < 1024; k0 += 32) {
    gll16(Ag + k0, Asd);
    gll16(Ag + 64 * 1024 + k0, Asd + 64 * 32);
    gll16(Bg + k0, Bsd);
    gll16(Bg + 64 * 1024 + k0, Bsd + 64 * 32);
    __syncthreads();
    bf16x8 af[4], bfr[4];
#pragma unroll
    for (int i = 0; i < 4; ++i) {
      af[i]  = ldfrag(As + (wm + 16 * i + c) * 32 + g * 8);
      bfr[i] = ldfrag(Bs + (wn + 16 * i + c) * 32 + g * 8);
    }
#pragma unroll
    for (int i = 0; i < 4; ++i)
#pragma unroll
      for (int j = 0; j < 4; ++j) {
        if (MODE == 2)
          acc[i][j] = __builtin_amdgcn_mfma_f32_16x16x32_bf16(af[i], bfr[j], acc[i][j], 0, 0, 0);
        else
          acc[i][j] = __builtin_amdgcn_mfma_f32_16x16x32_bf16(bfr[j], af[i], acc[i][j], 0, 0, 0);
      }
    __syncthreads();
  }

  if (MODE == 0) {
    // swapped: acc[i][j][r] = C[m = wm+16i+c][n = wn+16j+4g+r]
    u16* out = (u16*)Out;
    int nj[4], hj[4], dj[4];
    f32x4 bbj[4];
#pragma unroll
    for (int j = 0; j < 4; ++j) {
      nj[j] = n0 + wn + 16 * j + 4 * g;
      hj[j] = nj[j] >> 6; dj[j] = nj[j] & 63;
      f32x4 bb = *reinterpret_cast<const f32x4*>(&bias[nj[j]]);
#pragma unroll
      for (int r = 0; r < 4; ++r) bbj[j][r] = bb[r] * bscale;
    }
#pragma unroll
    for (int i = 0; i < 4; ++i) {
      int m = m0 + wm + 16 * i + c;
      int b2 = m >> 11, s2 = m & 2047;
#pragma unroll
      for (int j = 0; j < 4; ++j) {
        u16x4 o4;
#pragma unroll
        for (int r = 0; r < 4; ++r) o4[r] = f2bf(acc[i][j][r] + bbj[j][r]);
        *reinterpret_cast<u16x4*>(
            out + ((size_t)(b2 * 16 + hj[j]) * 2048 + s2) * 64 + dj[j]) = o4;
      }
    }
  } else {
    // V^T: unswapped acc (r -> s). Re-tile via tb[n_local 128][s_local 128 pad 136].
    u16* out = (u16*)Out;
    u16* tb = smem;
    float bvj[4];
#pragma unroll
    for (int j = 0; j < 4; ++j) bvj[j] = bias[n0 + wn + 16 * j + c];
#pragma unroll
    for (int i = 0; i < 4; ++i)
#pragma unroll
      for (int j = 0; j < 4; ++j) {
        u16x4 o4;
#pragma unroll
        for (int r = 0; r < 4; ++r) o4[r] = f2bf(acc[i][j][r] + bvj[j]);
        *reinterpret_cast<u16x4*>(&tb[(wn + 16 * j + c) * 136 + wm + 16 * i + 4 * g]) = o4;
      }
    __syncthreads();
    int b2 = m0 >> 11, s0 = m0 & 2047;
    int slot = lane & 15;
#pragma unroll
    for (int k = 0; k < 8; ++k) {
      int row = wave * 32 + k * 4 + (lane >> 4);   // n_local 0..127
      u16x8 v = *reinterpret_cast<const u16x8*>(&tb[row * 136 + slot * 8]);
      int n = n0 + row, h2 = n >> 6, d2 = n & 63;
      *reinterpret_cast<u16x8*>(
          out + ((size_t)(b2 * 16 + h2) * 64 + d2) * 2048 + s0 + slot * 8) = v;
    }
  }
}

__global__ __launch_bounds__(256) void qkv_gemm_kernel(
    const u16* __restrict__ xb, const u16* __restrict__ WT,
    const float* __restrict__ bq, const float* __restrict__ bk,
    const float* __restrict__ bv,
    u16* __restrict__ Q, u16* __restrict__ K, u16* __restrict__ V) {
  int z = blockIdx.z;
  const u16* Wt = WT + (size_t)z * 1024 * 1024;
  if (z == 0)      gemm_body<0>(xb, Wt, bq, QSCALE, Q);
  else if (z == 1) gemm_body<0>(xb, Wt, bk, 1.0f, K);
  else             gemm_body<2>(xb, Wt, bv, 1.0f, V);   // V stored transposed [B,H,HD,S]
}

// ---------------- out-projection: 512 threads (8 waves, 32x64 each), fp32 out ----------------
__global__ __launch_bounds__(512) void oproj_kernel(
    const u16* __restrict__ A, const u16* __restrict__ Wt,
    const float* __restrict__ bias, float* __restrict__ out) {
  __shared__ u16 As[128 * 32];
  __shared__ u16 Bs[128 * 32];
  int t = threadIdx.x;
  int lane = t & 63, wave = t >> 6;          // 8 waves
  int g = lane >> 4, c = lane & 15;
  int m0 = blockIdx.y * 128, n0 = blockIdx.x * 128;
  int wm = (wave >> 1) * 32, wn = (wave & 1) * 64;

  f32x4 acc[2][4] = {};

  const u16* Ag = A + (size_t)(m0 + (t >> 2)) * 1024 + (t & 3) * 8;
  const u16* Bg = Wt + (size_t)(n0 + (t >> 2)) * 1024 + (t & 3) * 8;
  u16* Asd = As + t * 8;     // 512 threads x 16B cover the full 8 KB tile
  u16* Bsd = Bs + t * 8;

  for (int k0 = 0; k0 < 1024; k0 += 32) {
    gll16(Ag + k0, Asd);
    gll16(Bg + k0, Bsd);
    __syncthreads();
    bf16x8 af[2], bfr[4];
#pragma unroll
    for (int i = 0; i < 2; ++i) af[i] = ldfrag(As + (wm + 16 * i + c) * 32 + g * 8);
#pragma unroll
    for (int j = 0; j < 4; ++j) bfr[j] = ldfrag(Bs + (wn + 16 * j + c) * 32 + g * 8);
#pragma unroll
    for (int i = 0; i < 2; ++i)
#pragma unroll
      for (int j = 0; j < 4; ++j)   // swapped: acc r -> n contiguous
        acc[i][j] = __builtin_amdgcn_mfma_f32_16x16x32_bf16(bfr[j], af[i], acc[i][j], 0, 0, 0);
    __syncthreads();
  }

  f32x4 bbj[4];
#pragma unroll
  for (int j = 0; j < 4; ++j)
    bbj[j] = *reinterpret_cast<const f32x4*>(&bias[n0 + wn + 16 * j + 4 * g]);
#pragma unroll
  for (int i = 0; i < 2; ++i) {
    int m = m0 + wm + 16 * i + c;
#pragma unroll
    for (int j = 0; j < 4; ++j) {
      f32x4 v = acc[i][j] + bbj[j];
      *reinterpret_cast<f32x4*>(out + (size_t)m * 1024 + n0 + wn + 16 * j + 4 * g) = v;
    }
  }
}

// ---------------- flash attention: 8 waves x 16q = 128 q/block, KVBLK=64 ----------------
// Triple-buffered K/V, 2-tile-ahead prefetch, counted vmcnt(2) BEFORE raw s_barrier
// (loads stay in flight across barriers — T3/T4 pattern). LDS 56 KB, grid 512 = 2 blk/CU.
__global__ __launch_bounds__(512) void attn_kernel(
    const u16* __restrict__ Q, const u16* __restrict__ K,
    const u16* __restrict__ V, u16* __restrict__ attn) {
  __shared__ u16 Kf[3][4096];
  __shared__ u16 Vt[3][4096];
  __shared__ u16 Pf[8][512];   // per-wave 1KB: 16q x 32kv bf16 (reused across m-halves)

  const int t = threadIdx.x;
  const int lane = t & 63, w = t >> 6;       // 8 waves
  const int g = lane >> 4, c = lane & 15;

  // XCD-aware bijective swizzle (nwg=512): each XCD's 64 blocks cover 4 (b,h) pairs
  int flat = blockIdx.x + 16 * (blockIdx.y + 16 * blockIdx.z);
  int sw = (flat & 7) * 64 + (flat >> 3);
  const int b = sw >> 8, h = (sw >> 4) & 15, q0 = (sw & 15) * 128;

  const u16* Qh = Q + ((size_t)(b * 16 + h) * 2048) * 64;
  const u16* Kh = K + ((size_t)(b * 16 + h) * 2048) * 64;
  const u16* VTh = V + ((size_t)(b * 16 + h) * 64) * 2048;

  const int qw = q0 + w * 16;
  bf16x8 qf0 = ldfrag(Qh + (size_t)(qw + c) * 64 + 8 * g);
  bf16x8 qf1 = ldfrag(Qh + (size_t)(qw + c) * 64 + 32 + 8 * g);

  bf16x8 ones;
  {
    u16x8 tmp;
#pragma unroll
    for (int l = 0; l < 8; ++l) tmp[l] = 0x3F80;
    ones = __builtin_bit_cast(bf16x8, tmp);
  }

  // per-wave staging sources (1 gll16 each for K and V per tile; dest = buf + t*8)
  // K: unit = w*64+lane -> row 16*(w>>1 & 3)+c, seg 32*(w&1)+8*g
  const u16* ksrc = Kh + (size_t)(16 * ((w >> 1) & 3) + c) * 64 + 32 * (w & 1) + 8 * g;
  // V^T: wave w covers d rows 8w..8w+7; XOR-swizzled kv slot
  const u16* vsrc = VTh + (size_t)(8 * w + (lane >> 3)) * 2048 +
                    (((lane & 7) ^ ((lane >> 3) & 7)) * 8);

  const int koff = g * 128 + c * 8;
  int vb_off[2];
#pragma unroll
  for (int m = 0; m < 2; ++m)
    vb_off[m] = c * 64 + (((4 * m + g) ^ (c & 7)) * 8);
  const int pa_off = (g * 16 + c) * 8;

  f32x4 o[4] = {};
  f32x4 lsum = {};
  float mrow = -3e38f;

  // ---- prologue: stage tiles 0 and 1; wait tile 0 only ----
  gll16(ksrc, &Kf[0][t * 8]);
  gll16(vsrc, &Vt[0][t * 8]);
  gll16(ksrc + 4096, &Kf[1][t * 8]);
  gll16(vsrc + 64, &Vt[1][t * 8]);
  asm volatile("s_waitcnt vmcnt(2)" ::: "memory");
  __builtin_amdgcn_s_barrier();
  asm volatile("" ::: "memory");

  int cur = 0;
  for (int tt32 = 0; tt32 < 32; ++tt32) {
    if (tt32 <= 29) {
      int nb = cur + 2; if (nb >= 3) nb -= 3;
      gll16(ksrc + (size_t)(tt32 + 2) * 4096, &Kf[nb][t * 8]);
      gll16(vsrc + (size_t)(tt32 + 2) * 64, &Vt[nb][t * 8]);
    }

    // ---- swapped QK^T: st[t4] = K(16 kv) . Q^T -> S^T[kv][q], q = c per lane ----
    const u16* kb = &Kf[cur][koff];
    f32x4 st[4];
    __builtin_amdgcn_s_setprio(1);
#pragma unroll
    for (int t4 = 0; t4 < 4; ++t4) {
      f32x4 acc = {};
      acc = __builtin_amdgcn_mfma_f32_16x16x32_bf16(
          ldfrag(kb + t4 * 1024), qf0, acc, 0, 0, 0);
      st[t4] = __builtin_amdgcn_mfma_f32_16x16x32_bf16(
          ldfrag(kb + t4 * 1024 + 512), qf1, acc, 0, 0, 0);
    }
    __builtin_amdgcn_s_setprio(0);

    // ---- online softmax over 64-kv tile (scores already in log2 units) ----
    float u1 = fm3(fm3(st[0][0], st[0][1], st[0][2]),
                   fm3(st[0][3], st[1][0], st[1][1]),
                   fm3(st[1][2], st[1][3], st[2][0]));
    float u2 = fm3(fm3(st[2][1], st[2][2], st[2][3]),
                   fm3(st[3][0], st[3][1], st[3][2]), st[3][3]);
    float tm = fmaxf(u1, u2);
    tm = fmaxf(tm, __shfl_xor(tm, 16));
    tm = fmaxf(tm, __shfl_xor(tm, 32));
    // T13 defer-max: only rescale when the max grew by >8 (log2 units; P <= 2^8)
    const bool grow = __any(tm > mrow + 8.0f);
    if (grow) {
      float nm = fmaxf(mrow, tm);
      float f = fexp2(mrow - nm);
      mrow = nm;
#pragma unroll
      for (int r = 0; r < 4; ++r) {
        float fr = __shfl(f, 4 * g + r);   // f lives at lanes indexed by q=c
        lsum[r] *= fr;
#pragma unroll
        for (int j = 0; j < 4; ++j) o[j][r] *= fr;
      }
    }
#pragma unroll
    for (int t4 = 0; t4 < 4; ++t4)
#pragma unroll
      for (int r = 0; r < 4; ++r) st[t4][r] = fexp2(st[t4][r] - mrow);

    // ---- pack P (per 32-kv half) into per-wave A-frag layout, then PV on that half ----
    u32* pd = (u32*)&Pf[w][0];
#pragma unroll
    for (int m = 0; m < 2; ++m) {
#pragma unroll
      for (int tp = 0; tp < 2; ++tp) {
        int t4 = 2 * m + tp;
        u32 w0 = cvt_pk_bf16(st[t4][0], st[t4][1]);
        u32 w1 = cvt_pk_bf16(st[t4][2], st[t4][3]);
        int gp = (2 * t4 + (g >> 1)) & 3;
        int base = (gp * 16 + c) * 4 + 2 * (g & 1);
        *reinterpret_cast<u64*>(&pd[base]) = (u64)w0 | ((u64)w1 << 32);
      }
      bf16x8 pa = ldfrag(&Pf[w][pa_off]);
      __builtin_amdgcn_s_setprio(1);
#pragma unroll
      for (int j = 0; j < 4; ++j) {
        bf16x8 vb = ldfrag(&Vt[cur][vb_off[m] + j * 1024]);
        o[j] = __builtin_amdgcn_mfma_f32_16x16x32_bf16(pa, vb, o[j], 0, 0, 0);
      }
      lsum = __builtin_amdgcn_mfma_f32_16x16x32_bf16(pa, ones, lsum, 0, 0, 0);
      __builtin_amdgcn_s_setprio(0);
    }

    // counted wait: drain next tile's loads only; keep tile+2 in flight across barrier
    if (tt32 <= 29)
      asm volatile("s_waitcnt vmcnt(2)" ::: "memory");
    else if (tt32 == 30)
      asm volatile("s_waitcnt vmcnt(0)" ::: "memory");
    if (tt32 < 31) {
      __builtin_amdgcn_s_barrier();
      asm volatile("" ::: "memory");
    }
    ++cur; if (cur == 3) cur = 0;
  }

  // ---- epilogue: normalize, write attn[B,S,D] (O lane layout: q=4g+r, d=16j+c) ----
  float rinv[4];
#pragma unroll
  for (int r = 0; r < 4; ++r) rinv[r] = 1.f / lsum[r];
#pragma unroll
  for (int j = 0; j < 4; ++j)
#pragma unroll
    for (int r = 0; r < 4; ++r) {
      int s = qw + 4 * g + r;
      attn[(size_t)(b * 2048 + s) * 1024 + h * 64 + 16 * j + c] = f2bf(o[j][r] * rinv[r]);
    }
}

extern "C" void kernel_launch(void* const* d_in, const int* in_sizes, int n_in,
                              void* d_out, int out_size, void* d_ws, size_t ws_size,
                              hipStream_t stream) {
  const float* x  = (const float*)d_in[0];
  const float* Wq = (const float*)d_in[1];
  const float* bq = (const float*)d_in[2];
  const float* Wk = (const float*)d_in[3];
  const float* bk = (const float*)d_in[4];
  const float* Wv = (const float*)d_in[5];
  const float* bv = (const float*)d_in[6];
  const float* Wo = (const float*)d_in[7];
  const float* bo = (const float*)d_in[8];
  float* out = (float*)d_out;
  u16* ws = (u16*)d_ws;

  // workspace layout (u16 elems): xb 4M | WT 4x1M | Q 4M | K 4M | V^T 4M  => 40 MB
  u16* xb    = ws;
  u16* WT    = ws + (size_t)4 * 1024 * 1024;
  u16* Qb    = ws + (size_t)8 * 1024 * 1024;
  u16* Kb    = ws + (size_t)12 * 1024 * 1024;
  u16* Vb    = ws + (size_t)16 * 1024 * 1024;
  u16* attnb = xb;  // xb dead after QKV GEMM; reuse for attn output

  cast_x_kernel<<<2048, 256, 0, stream>>>(x, xb);
  transpose_w_kernel<<<dim3(16, 16, 4), 256, 0, stream>>>(Wq, Wk, Wv, Wo, WT);
  qkv_gemm_kernel<<<dim3(8, 32, 3), 256, 0, stream>>>(xb, WT, bq, bk, bv, Qb, Kb, Vb);
  attn_kernel<<<dim3(16, 16, 2), 512, 0, stream>>>(Qb, Kb, Vb, attnb);
  oproj_kernel<<<dim3(8, 32), 512, 0, stream>>>(attnb, WT + (size_t)3 * 1024 * 1024, bo, out);
}